// Round 5
// baseline (1417.906 us; speedup 1.0000x reference)
//
#include <hip/hip_runtime.h>
#include <math.h>

typedef unsigned short u16;
typedef unsigned int u32;

// B=64, L=256, DIN=768, H=64, E=8, K=2, S=16; BL=16384
// ALL inputs are float32 (per reference); output is float32 (out plane + loss scalar).

__device__ __forceinline__ float bf2f(u16 u) {
    union { u32 i; float f; } x; x.i = ((u32)u) << 16; return x.f;
}
__device__ __forceinline__ u16 f2bf(float f) {
    union { float f; u32 i; } x; x.f = f;
    u32 i = x.i;
    return (u16)((i + 0x7fffu + ((i >> 16) & 1u)) >> 16);
}
__device__ __forceinline__ float wsum(float v) {
    #pragma unroll
    for (int o = 1; o < 64; o <<= 1) v += __shfl_xor(v, o, 64);
    return v;
}
__device__ __forceinline__ float gelu_f(float x) {
    return 0.5f * x * (1.0f + erff(x * 0.70710678118654752440f));
}

// ---------- kernel 1: per-batch gating -> 8 gate floats per batch, written into
// the head of the output plane (scratch; k_mega overwrites the whole plane later).
__global__ __launch_bounds__(256) void k_gates(const float* __restrict__ dte,
                                               const float* __restrict__ w_gate,
                                               float* __restrict__ gatesF) {
    __shared__ float dmeanS[256];
    __shared__ float logitsS[8];
    int b = blockIdx.x, tid = threadIdx.x, w = tid >> 6, lane = tid & 63;
    for (int l = w; l < 256; l += 4) {
        const float* p = dte + (size_t)(b * 256 + l) * 768;
        float s = 0.f;
        #pragma unroll
        for (int j = 0; j < 12; j++) s += p[j * 64 + lane];
        s = wsum(s);
        if (lane == 0) dmeanS[l] = s * (1.f / 768.f);
    }
    __syncthreads();
    if (w == 0) {
        float acc[8];
        #pragma unroll
        for (int e = 0; e < 8; e++) acc[e] = 0.f;
        for (int l = lane; l < 256; l += 64) {
            float dm = dmeanS[l];
            #pragma unroll
            for (int e = 0; e < 8; e++) acc[e] += dm * w_gate[l * 8 + e];
        }
        #pragma unroll
        for (int e = 0; e < 8; e++) {
            float s = wsum(acc[e]);
            if (lane == 0) logitsS[e] = s;
        }
    }
    __syncthreads();
    if (tid == 0) {
        float lg[8];
        #pragma unroll
        for (int e = 0; e < 8; e++) lg[e] = logitsS[e];
        int i0 = 0; float v0 = lg[0];
        #pragma unroll
        for (int e = 1; e < 8; e++) if (lg[e] > v0) { v0 = lg[e]; i0 = e; }
        int i1 = -1; float v1 = -1e30f;
        #pragma unroll
        for (int e = 0; e < 8; e++) if (e != i0 && lg[e] > v1) { v1 = lg[e]; i1 = e; }
        if (i1 < 0) i1 = (i0 + 1) & 7;   // defensive (NaN logits)
        float e2 = expf(v1 - v0);
        float g0 = 1.f / (1.f + e2);
        float g1 = e2 / (1.f + e2);
        #pragma unroll
        for (int e = 0; e < 8; e++) gatesF[b * 8 + e] = 0.f;
        gatesF[b * 8 + i0] = g0;
        gatesF[b * 8 + i1] = g1;
    }
}

// ---------- kernel 2: aux loss from the 512 gate floats; writes out[1048576] (f32).
__global__ void k_loss(const float* __restrict__ gatesF, float* __restrict__ loss_out) {
    int t = threadIdx.x;  // 64 lanes, lane t = batch t
    float g[8];
    #pragma unroll
    for (int e = 0; e < 8; e++) g[e] = gatesF[t * 8 + e];
    float imp[8], ld[8];
    #pragma unroll
    for (int e = 0; e < 8; e++) {
        imp[e] = wsum(g[e]);
        ld[e]  = wsum(g[e] > 0.f ? 1.f : 0.f);
    }
    if (t == 0) {
        float l = 0.f;
        {
            float s = 0.f;
            #pragma unroll
            for (int e = 0; e < 8; e++) s += imp[e];
            float mn = s / 8.f;
            float v = 0.f;
            #pragma unroll
            for (int e = 0; e < 8; e++) { float d = imp[e] - mn; v += d * d; }
            v /= 7.f;
            l += v / (mn * mn + 1e-10f);
        }
        {
            float s = 0.f;
            #pragma unroll
            for (int e = 0; e < 8; e++) s += ld[e];
            float mn = s / 8.f;
            float v = 0.f;
            #pragma unroll
            for (int e = 0; e < 8; e++) { float d = ld[e] - mn; v += d * d; }
            v /= 7.f;
            l += v / (mn * mn + 1e-10f);
        }
        loss_out[0] = 0.01f * l;
    }
}

// ---------- kernel 3: per-batch mega-kernel. 64 blocks x 1024 threads. 64 KB LDS.
//   T1 = pool[0:32768)      bf16 256x64 plane (t1 -> y -> rgb)
//   T2 = pool[32768:65536)  bf16 256x64 plane (t2 -> dte_tok); f32 GEMM staging overlay
//   R  = out + b*16384      f32 256x64 plane (sh -> sh2 -> final out), block-exclusive
__global__ __launch_bounds__(1024) void k_mega(
    const float* __restrict__ x, const float* __restrict__ dte,
    const float* __restrict__ w_gate, const float* __restrict__ W_exp, const float* __restrict__ b_exp,
    const float* __restrict__ W_sh, const float* __restrict__ b_sh,
    const float* __restrict__ ln_g, const float* __restrict__ ln_b,
    const float* __restrict__ W_px, const float* __restrict__ b_px,
    const float* __restrict__ conv_sh, const float* __restrict__ W_pxx, const float* __restrict__ b_pxx,
    const float* __restrict__ W_dte, const float* __restrict__ b_dte,
    const float* __restrict__ W_dteall, const float* __restrict__ b_dteall,
    const float* __restrict__ W_rgb, const float* __restrict__ b_rgb,
    const float* __restrict__ W_fx, const float* __restrict__ b_fx,
    const float* __restrict__ W_fmod, const float* __restrict__ b_fmod,
    const float* __restrict__ W_fxx, const float* __restrict__ b_fxx,
    float* __restrict__ out)
{
    __shared__ __align__(16) char pool[65536];
    u16* T1 = (u16*)pool;
    u16* T2 = (u16*)(pool + 32768);
    float* As = (float*)(pool + 32768);      // 64x64 f32 staging (T2 area, only when T2 dead)
    float* Ws = (float*)(pool + 49152);      // 64x64 f32 staging
    float* dmeanS = (float*)pool;            // stage-1 overlay (T1 area, before T1 live)
    float* logitsS = (float*)(pool + 1024);

    const int b = blockIdx.x;
    const int tid = threadIdx.x;
    const int w = tid >> 6;       // wave 0..15
    const int lane = tid & 63;
    float* R = out + (size_t)b * 16384;

    // ===== stage 1: gating (local recompute; cross-batch loss handled elsewhere) =====
    for (int l = w; l < 256; l += 16) {
        const float* p = dte + ((size_t)(b * 256 + l)) * 768;
        float s = 0.f;
        #pragma unroll
        for (int j = 0; j < 12; j++) s += p[j * 64 + lane];
        s = wsum(s);
        if (lane == 0) dmeanS[l] = s * (1.f / 768.f);
    }
    __syncthreads();
    if (w == 0) {
        float acc[8];
        #pragma unroll
        for (int e = 0; e < 8; e++) acc[e] = 0.f;
        for (int l = lane; l < 256; l += 64) {
            float dm = dmeanS[l];
            #pragma unroll
            for (int e = 0; e < 8; e++) acc[e] += dm * w_gate[l * 8 + e];
        }
        #pragma unroll
        for (int e = 0; e < 8; e++) {
            float s = wsum(acc[e]);
            if (lane == 0) logitsS[e] = s;
        }
    }
    __syncthreads();
    float lg[8];
    #pragma unroll
    for (int e = 0; e < 8; e++) lg[e] = logitsS[e];
    int i0 = 0; float v0 = lg[0];
    #pragma unroll
    for (int e = 1; e < 8; e++) if (lg[e] > v0) { v0 = lg[e]; i0 = e; }
    int i1 = -1; float v1 = -1e30f;
    #pragma unroll
    for (int e = 0; e < 8; e++) if (e != i0 && lg[e] > v1) { v1 = lg[e]; i1 = e; }
    if (i1 < 0) i1 = (i0 + 1) & 7;       // defensive: never index with -1
    float e2 = expf(v1 - v0);
    float g0 = 1.f / (1.f + e2);
    float g1 = e2 / (1.f + e2);
    __syncthreads();

    // ===== stage 2: sh = dte_b @ W_sh + b_sh -> R (f32) =====
    {
        float bs = b_sh[lane];
        for (int grp = 0; grp < 4; grp++) {
            int row0 = grp * 64;
            float a0 = 0.f, a1 = 0.f, a2 = 0.f, a3 = 0.f;
            for (int kc = 0; kc < 12; kc++) {
                __syncthreads();
                #pragma unroll
                for (int j = 0; j < 4; j++) {
                    int u = tid + j * 1024;
                    int r = u >> 6, k = u & 63;
                    As[r * 64 + k] = dte[((size_t)(b * 256 + row0 + r)) * 768 + kc * 64 + k];
                }
                #pragma unroll
                for (int j = 0; j < 4; j++) {
                    int e = tid + j * 1024;
                    int k = e >> 6, h = e & 63;
                    Ws[k * 64 + h] = W_sh[(size_t)(kc * 64 + k) * 64 + h];
                }
                __syncthreads();
                #pragma unroll 8
                for (int kk = 0; kk < 64; kk++) {
                    float wv = Ws[kk * 64 + lane];
                    const float* ar = As + (w * 4) * 64 + kk;
                    a0 += ar[0]   * wv;
                    a1 += ar[64]  * wv;
                    a2 += ar[128] * wv;
                    a3 += ar[192] * wv;
                }
            }
            int l0 = row0 + w * 4;
            R[(l0 + 0) * 64 + lane] = a0 + bs;
            R[(l0 + 1) * 64 + lane] = a1 + bs;
            R[(l0 + 2) * 64 + lane] = a2 + bs;
            R[(l0 + 3) * 64 + lane] = a3 + bs;
        }
    }
    __syncthreads();

    // ===== stage 3: t = LN(sh)*g+b; [t1|t2] = t @ W_px + b_px -> T1,T2 (bf16) =====
    {
        float lnG = ln_g[lane], lnB = ln_b[lane];
        float bp1 = b_px[lane], bp2 = b_px[64 + lane];
        for (int l = w; l < 256; l += 16) {
            float v = R[l * 64 + lane];
            float mean = wsum(v) * (1.f / 64.f);
            float d = v - mean;
            float var = wsum(d * d) * (1.f / 64.f);
            float t = d * rsqrtf(var + 1e-6f) * lnG + lnB;
            float a1 = bp1, a2 = bp2;
            #pragma unroll 8
            for (int k = 0; k < 64; k++) {
                float tk = __shfl(t, k, 64);
                a1 += tk * W_px[k * 128 + lane];
                a2 += tk * W_px[k * 128 + 64 + lane];
            }
            T1[l * 64 + lane] = f2bf(a1);
            T2[l * 64 + lane] = f2bf(a2);
        }
    }
    __syncthreads();

    // ===== stage 4: sh2 = gelu(conv(t1))*t2 @ W_pxx + b_pxx + sh -> R =====
    {
        float c0 = conv_sh[lane * 9 + 0], c1 = conv_sh[lane * 9 + 1], c2 = conv_sh[lane * 9 + 2];
        float c3 = conv_sh[lane * 9 + 3], c4 = conv_sh[lane * 9 + 4], c5 = conv_sh[lane * 9 + 5];
        float c6 = conv_sh[lane * 9 + 6], c7 = conv_sh[lane * 9 + 7], c8 = conv_sh[lane * 9 + 8];
        float bpx = b_pxx[lane];
        for (int l = w; l < 256; l += 16) {
            int ii = l >> 4, jj = l & 15;
            const u16* p = T1 + l * 64 + lane;
            float c = c4 * bf2f(p[0]);
            if (ii > 0) {
                c += c1 * bf2f(p[-1024]);
                if (jj > 0)  c += c0 * bf2f(p[-1024 - 64]);
                if (jj < 15) c += c2 * bf2f(p[-1024 + 64]);
            }
            if (jj > 0)  c += c3 * bf2f(p[-64]);
            if (jj < 15) c += c5 * bf2f(p[64]);
            if (ii < 15) {
                c += c7 * bf2f(p[1024]);
                if (jj > 0)  c += c6 * bf2f(p[1024 - 64]);
                if (jj < 15) c += c8 * bf2f(p[1024 + 64]);
            }
            float u = gelu_f(c) * bf2f(T2[l * 64 + lane]);
            float a = bpx + R[l * 64 + lane];
            #pragma unroll 8
            for (int k = 0; k < 64; k++) a += __shfl(u, k, 64) * W_pxx[k * 64 + lane];
            R[l * 64 + lane] = a;
        }
    }
    __syncthreads();

    // ===== stage 5: y = dte_b @ (g0*W_exp[i0]+g1*W_exp[i1]) + (g0*b0+g1*b1) -> T1 =====
    {
        const float* W0 = W_exp + (size_t)i0 * 49152;
        const float* W1 = W_exp + (size_t)i1 * 49152;
        float by = g0 * b_exp[i0 * 64 + lane] + g1 * b_exp[i1 * 64 + lane];
        for (int grp = 0; grp < 4; grp++) {
            int row0 = grp * 64;
            float a0 = 0.f, a1 = 0.f, a2 = 0.f, a3 = 0.f;
            for (int kc = 0; kc < 12; kc++) {
                __syncthreads();
                #pragma unroll
                for (int j = 0; j < 4; j++) {
                    int u = tid + j * 1024;
                    int r = u >> 6, k = u & 63;
                    As[r * 64 + k] = dte[((size_t)(b * 256 + row0 + r)) * 768 + kc * 64 + k];
                }
                #pragma unroll
                for (int j = 0; j < 4; j++) {
                    int e = tid + j * 1024;
                    int k = e >> 6, h = e & 63;
                    size_t wi = (size_t)(kc * 64 + k) * 64 + h;
                    Ws[k * 64 + h] = g0 * W0[wi] + g1 * W1[wi];
                }
                __syncthreads();
                #pragma unroll 8
                for (int kk = 0; kk < 64; kk++) {
                    float wv = Ws[kk * 64 + lane];
                    const float* ar = As + (w * 4) * 64 + kk;
                    a0 += ar[0]   * wv;
                    a1 += ar[64]  * wv;
                    a2 += ar[128] * wv;
                    a3 += ar[192] * wv;
                }
            }
            int l0 = row0 + w * 4;
            T1[(l0 + 0) * 64 + lane] = f2bf(a0 + by);
            T1[(l0 + 1) * 64 + lane] = f2bf(a1 + by);
            T1[(l0 + 2) * 64 + lane] = f2bf(a2 + by);
            T1[(l0 + 3) * 64 + lane] = f2bf(a3 + by);
        }
    }
    __syncthreads();

    // ===== stage 6: dte_tok = y@W_dte + sh2@W_dteall + biases -> T2 =====
    {
        float bdt = b_dte[lane] + b_dteall[lane];
        for (int l = w; l < 256; l += 16) {
            float yv = bf2f(T1[l * 64 + lane]);
            float sv = R[l * 64 + lane];
            float a = bdt;
            #pragma unroll 8
            for (int k = 0; k < 64; k++) {
                a += __shfl(yv, k, 64) * W_dte[k * 64 + lane];
                a += __shfl(sv, k, 64) * W_dteall[k * 64 + lane];
            }
            T2[l * 64 + lane] = f2bf(a);
        }
    }
    __syncthreads();

    // ===== stage 7: rgb = x_b @ W_rgb + b_rgb -> T1 (global-direct, 4-row blocking) =====
    {
        float brg = b_rgb[lane];
        for (int it = 0; it < 4; it++) {
            int l0 = it * 64 + w * 4;
            float a0 = brg, a1 = brg, a2 = brg, a3 = brg;
            const float* x0 = x + ((size_t)(b * 256 + l0)) * 768;
            #pragma unroll 4
            for (int kp = 0; kp < 768; kp++) {
                float wv = W_rgb[(size_t)kp * 64 + lane];
                a0 += x0[kp]        * wv;
                a1 += x0[768 + kp]  * wv;
                a2 += x0[1536 + kp] * wv;
                a3 += x0[2304 + kp] * wv;
            }
            T1[(l0 + 0) * 64 + lane] = f2bf(a0);
            T1[(l0 + 1) * 64 + lane] = f2bf(a1);
            T1[(l0 + 2) * 64 + lane] = f2bf(a2);
            T1[(l0 + 3) * 64 + lane] = f2bf(a3);
        }
    }
    __syncthreads();

    // ===== stage 8: out = (gelu(m)*a)@W_fxx + b_fxx + rgb -> R (final, f32) =====
    {
        float bfx = b_fx[lane], bfm = b_fmod[lane], bfo = b_fxx[lane];
        for (int l = w; l < 256; l += 16) {
            float rv = bf2f(T1[l * 64 + lane]);
            float gav = gelu_f(rv);
            float gmv = gelu_f(bf2f(T2[l * 64 + lane]));
            float aa = bfx, mm = bfm;
            #pragma unroll 8
            for (int k = 0; k < 64; k++) {
                aa += __shfl(gav, k, 64) * W_fx[k * 64 + lane];
                mm += __shfl(gmv, k, 64) * W_fmod[k * 64 + lane];
            }
            float p = gelu_f(mm) * aa;
            float o = bfo + rv;
            #pragma unroll 8
            for (int k = 0; k < 64; k++) o += __shfl(p, k, 64) * W_fxx[k * 64 + lane];
            R[l * 64 + lane] = o;
        }
    }
}

extern "C" void kernel_launch(void* const* d_in, const int* in_sizes, int n_in,
                              void* d_out, int out_size, void* d_ws, size_t ws_size,
                              hipStream_t stream) {
    const float* x       = (const float*)d_in[0];
    const float* dte     = (const float*)d_in[1];
    const float* w_gate  = (const float*)d_in[2];
    const float* W_exp   = (const float*)d_in[3];
    const float* b_exp   = (const float*)d_in[4];
    const float* W_sh    = (const float*)d_in[5];
    const float* b_sh    = (const float*)d_in[6];
    const float* ln_g    = (const float*)d_in[7];
    const float* ln_b    = (const float*)d_in[8];
    const float* W_px    = (const float*)d_in[9];
    const float* b_px    = (const float*)d_in[10];
    const float* conv_sh = (const float*)d_in[11];
    const float* W_pxx   = (const float*)d_in[12];
    const float* b_pxx   = (const float*)d_in[13];
    const float* W_dte   = (const float*)d_in[14];
    const float* b_dte   = (const float*)d_in[15];
    const float* W_dteall= (const float*)d_in[16];
    const float* b_dteall= (const float*)d_in[17];
    const float* W_rgb   = (const float*)d_in[18];
    const float* b_rgb   = (const float*)d_in[19];
    const float* W_fx    = (const float*)d_in[20];
    const float* b_fx    = (const float*)d_in[21];
    const float* W_fmod  = (const float*)d_in[22];
    const float* b_fmod  = (const float*)d_in[23];
    const float* W_fxx   = (const float*)d_in[24];
    const float* b_fxx   = (const float*)d_in[25];

    float* out = (float*)d_out;        // [0,1048576) out plane (f32) + loss at [1048576]
    float* gatesF = out;               // first 512 floats of plane, pre-stage scratch

    // 1) gates -> head of out plane (scratch)
    hipLaunchKernelGGL(k_gates, dim3(64), dim3(256), 0, stream, dte, w_gate, gatesF);
    // 2) loss from gates -> out[1048576] (slot never touched again)
    hipLaunchKernelGGL(k_loss, dim3(1), dim3(64), 0, stream, gatesF, out + 1048576);
    // 3) everything else; overwrites the entire out plane with the real output
    hipLaunchKernelGGL(k_mega, dim3(64), dim3(1024), 0, stream,
                       x, dte, w_gate, W_exp, b_exp, W_sh, b_sh, ln_g, ln_b,
                       W_px, b_px, conv_sh, W_pxx, b_pxx, W_dte, b_dte,
                       W_dteall, b_dteall, W_rgb, b_rgb, W_fx, b_fx,
                       W_fmod, b_fmod, W_fxx, b_fxx, out);

    (void)in_sizes; (void)n_in; (void)out_size; (void)d_ws; (void)ws_size;
}

// Round 6
// 363.732 us; speedup vs baseline: 3.8982x; 3.8982x over previous
//
#include <hip/hip_runtime.h>
#include <math.h>

typedef unsigned short u16;
typedef unsigned int u32;

// B=64, L=256, DIN=768, H=64, E=8, K=2, S=16; BL=16384. All inputs f32, output f32.

__device__ __forceinline__ float bf2f(u16 u) {
    union { u32 i; float f; } x; x.i = ((u32)u) << 16; return x.f;
}
__device__ __forceinline__ u16 f2bf(float f) {
    union { float f; u32 i; } x; x.f = f;
    u32 i = x.i;
    return (u16)((i + 0x7fffu + ((i >> 16) & 1u)) >> 16);
}
__device__ __forceinline__ u32 pack2(float a, float b) {
    return (u32)f2bf(a) | ((u32)f2bf(b) << 16);
}
__device__ __forceinline__ float wsum(float v) {
    #pragma unroll
    for (int o = 1; o < 64; o <<= 1) v += __shfl_xor(v, o, 64);
    return v;
}
__device__ __forceinline__ float gelu_f(float x) {
    return 0.5f * x * (1.0f + erff(x * 0.70710678118654752440f));
}

// ---------- 1. gating: gates, topi, topg, bias_y ----------
__global__ __launch_bounds__(256) void k_gates(const float* __restrict__ dte,
                                               const float* __restrict__ w_gate,
                                               const float* __restrict__ b_exp,
                                               float* __restrict__ gates,
                                               int* __restrict__ topi,
                                               float* __restrict__ topg,
                                               float* __restrict__ bias_y) {
    __shared__ float dmeanS[256];
    __shared__ float logitsS[8];
    __shared__ int shI[2];
    __shared__ float shG[2];
    int b = blockIdx.x, tid = threadIdx.x, w = tid >> 6, lane = tid & 63;
    for (int l = w; l < 256; l += 4) {
        const float* p = dte + (size_t)(b * 256 + l) * 768;
        float s = 0.f;
        #pragma unroll
        for (int j = 0; j < 12; j++) s += p[j * 64 + lane];
        s = wsum(s);
        if (lane == 0) dmeanS[l] = s * (1.f / 768.f);
    }
    __syncthreads();
    if (w == 0) {
        float acc[8];
        #pragma unroll
        for (int e = 0; e < 8; e++) acc[e] = 0.f;
        for (int l = lane; l < 256; l += 64) {
            float dm = dmeanS[l];
            #pragma unroll
            for (int e = 0; e < 8; e++) acc[e] += dm * w_gate[l * 8 + e];
        }
        #pragma unroll
        for (int e = 0; e < 8; e++) {
            float s = wsum(acc[e]);
            if (lane == 0) logitsS[e] = s;
        }
    }
    __syncthreads();
    if (tid == 0) {
        float lg[8];
        #pragma unroll
        for (int e = 0; e < 8; e++) lg[e] = logitsS[e];
        int i0 = 0; float v0 = lg[0];
        #pragma unroll
        for (int e = 1; e < 8; e++) if (lg[e] > v0) { v0 = lg[e]; i0 = e; }
        int i1 = -1; float v1 = -1e30f;
        #pragma unroll
        for (int e = 0; e < 8; e++) if (e != i0 && lg[e] > v1) { v1 = lg[e]; i1 = e; }
        if (i1 < 0) i1 = (i0 + 1) & 7;
        float e2 = expf(v1 - v0);
        float g0 = 1.f / (1.f + e2);
        float g1 = e2 / (1.f + e2);
        #pragma unroll
        for (int e = 0; e < 8; e++) gates[b * 8 + e] = 0.f;
        gates[b * 8 + i0] = g0;
        gates[b * 8 + i1] = g1;
        topi[b * 2] = i0; topi[b * 2 + 1] = i1;
        topg[b * 2] = g0; topg[b * 2 + 1] = g1;
        shI[0] = i0; shI[1] = i1; shG[0] = g0; shG[1] = g1;
    }
    __syncthreads();
    if (tid < 64) {
        bias_y[b * 64 + tid] = shG[0] * b_exp[shI[0] * 64 + tid] +
                               shG[1] * b_exp[shI[1] * 64 + tid];
    }
}

// ---------- 2. aux loss ----------
__global__ void k_loss(const float* __restrict__ gates, float* __restrict__ loss_out) {
    int t = threadIdx.x;  // lane t = batch t
    float g[8];
    #pragma unroll
    for (int e = 0; e < 8; e++) g[e] = gates[t * 8 + e];
    float imp[8], ld[8];
    #pragma unroll
    for (int e = 0; e < 8; e++) {
        imp[e] = wsum(g[e]);
        ld[e]  = wsum(g[e] > 0.f ? 1.f : 0.f);
    }
    if (t == 0) {
        float l = 0.f;
        {
            float s = 0.f;
            #pragma unroll
            for (int e = 0; e < 8; e++) s += imp[e];
            float mn = s / 8.f, v = 0.f;
            #pragma unroll
            for (int e = 0; e < 8; e++) { float d = imp[e] - mn; v += d * d; }
            l += (v / 7.f) / (mn * mn + 1e-10f);
        }
        {
            float s = 0.f;
            #pragma unroll
            for (int e = 0; e < 8; e++) s += ld[e];
            float mn = s / 8.f, v = 0.f;
            #pragma unroll
            for (int e = 0; e < 8; e++) { float d = ld[e] - mn; v += d * d; }
            l += (v / 7.f) / (mn * mn + 1e-10f);
        }
        loss_out[0] = 0.01f * l;
    }
}

// ---------- 3. big GEMMs: blocks 0-255 -> sh (f32), 256-511 -> y (bf16) ----------
__global__ __launch_bounds__(256) void k_gemm_sh_y(const float* __restrict__ dte,
                                                   const float* __restrict__ W_sh,
                                                   const float* __restrict__ b_sh,
                                                   const float* __restrict__ W_exp,
                                                   const int* __restrict__ topi,
                                                   const float* __restrict__ topg,
                                                   const float* __restrict__ bias_y,
                                                   float* __restrict__ buf_sh,
                                                   u16* __restrict__ buf_y) {
    __shared__ float As[64 * 68];
    __shared__ float Ws[64 * 68];
    int bid = blockIdx.x;
    int is_y = bid >> 8;
    int row0 = (bid & 255) * 64;
    int b = row0 >> 8;
    int tid = threadIdx.x, rg = tid >> 4, cg = tid & 15;
    const float* W0 = W_sh;
    const float* W1 = W_sh;
    float g0 = 0.f, g1 = 0.f;
    if (is_y) {
        W0 = W_exp + (size_t)topi[2 * b] * 49152;
        W1 = W_exp + (size_t)topi[2 * b + 1] * 49152;
        g0 = topg[2 * b]; g1 = topg[2 * b + 1];
    }
    float acc[4][4] = {};
    for (int kc = 0; kc < 12; kc++) {
        __syncthreads();
        #pragma unroll
        for (int j = 0; j < 4; j++) {
            int e4 = tid + j * 256;
            int r = e4 >> 4, kq = e4 & 15;
            float4 v = *(const float4*)(dte + (size_t)(row0 + r) * 768 + kc * 64 + kq * 4);
            *(float4*)(As + r * 68 + kq * 4) = v;
        }
        #pragma unroll
        for (int j = 0; j < 4; j++) {
            int e4 = tid + j * 256;
            int k = e4 >> 4, hq = e4 & 15;
            size_t off = (size_t)(kc * 64 + k) * 64 + hq * 4;
            float4 wv;
            if (is_y) {
                float4 a = *(const float4*)(W0 + off);
                float4 c = *(const float4*)(W1 + off);
                wv.x = g0 * a.x + g1 * c.x; wv.y = g0 * a.y + g1 * c.y;
                wv.z = g0 * a.z + g1 * c.z; wv.w = g0 * a.w + g1 * c.w;
            } else {
                wv = *(const float4*)(W_sh + off);
            }
            *(float4*)(Ws + k * 68 + hq * 4) = wv;
        }
        __syncthreads();
        const float* ar = As + rg * 4 * 68;
        #pragma unroll 8
        for (int kk = 0; kk < 64; kk++) {
            float a0 = ar[kk], a1 = ar[68 + kk], a2 = ar[136 + kk], a3 = ar[204 + kk];
            float4 wv = *(const float4*)(Ws + kk * 68 + cg * 4);
            acc[0][0] += a0 * wv.x; acc[0][1] += a0 * wv.y; acc[0][2] += a0 * wv.z; acc[0][3] += a0 * wv.w;
            acc[1][0] += a1 * wv.x; acc[1][1] += a1 * wv.y; acc[1][2] += a1 * wv.z; acc[1][3] += a1 * wv.w;
            acc[2][0] += a2 * wv.x; acc[2][1] += a2 * wv.y; acc[2][2] += a2 * wv.z; acc[2][3] += a2 * wv.w;
            acc[3][0] += a3 * wv.x; acc[3][1] += a3 * wv.y; acc[3][2] += a3 * wv.z; acc[3][3] += a3 * wv.w;
        }
    }
    if (!is_y) {
        float4 bs = *(const float4*)(b_sh + cg * 4);
        #pragma unroll
        for (int i = 0; i < 4; i++) {
            int r = row0 + rg * 4 + i;
            float4 o = make_float4(acc[i][0] + bs.x, acc[i][1] + bs.y, acc[i][2] + bs.z, acc[i][3] + bs.w);
            *(float4*)(buf_sh + (size_t)r * 64 + cg * 4) = o;
        }
    } else {
        float4 by = *(const float4*)(bias_y + b * 64 + cg * 4);
        #pragma unroll
        for (int i = 0; i < 4; i++) {
            int r = row0 + rg * 4 + i;
            u32* dst = (u32*)(buf_y + (size_t)r * 64 + cg * 4);
            dst[0] = pack2(acc[i][0] + by.x, acc[i][1] + by.y);
            dst[1] = pack2(acc[i][2] + by.z, acc[i][3] + by.w);
        }
    }
}

// ---------- 4. LN + W_px -> t1, t2 (bf16) ----------
__global__ __launch_bounds__(256) void k_lnpx(const float* __restrict__ buf_sh,
                                              const float* __restrict__ ln_g,
                                              const float* __restrict__ ln_b,
                                              const float* __restrict__ W_px,
                                              const float* __restrict__ b_px,
                                              u16* __restrict__ t1, u16* __restrict__ t2) {
    __shared__ float T[64 * 68];
    __shared__ float Wpx[8192];
    int row0 = blockIdx.x * 64;
    int tid = threadIdx.x, w = tid >> 6, lane = tid & 63;
    #pragma unroll
    for (int j = 0; j < 8; j++) {
        int e4 = tid + j * 256;
        *(float4*)(Wpx + e4 * 4) = *(const float4*)(W_px + e4 * 4);
    }
    float lnG = ln_g[lane], lnB = ln_b[lane];
    for (int i = 0; i < 16; i++) {
        int l = i * 4 + w;
        float v = buf_sh[(size_t)(row0 + l) * 64 + lane];
        float mean = wsum(v) * (1.f / 64.f);
        float d = v - mean;
        float var = wsum(d * d) * (1.f / 64.f);
        T[l * 68 + lane] = d * rsqrtf(var + 1e-6f) * lnG + lnB;
    }
    __syncthreads();
    int rg = tid >> 4, cg = tid & 15;
    float acc1[4][4] = {}, acc2[4][4] = {};
    const float* tr = T + rg * 4 * 68;
    #pragma unroll 4
    for (int kk = 0; kk < 64; kk++) {
        float a0 = tr[kk], a1 = tr[68 + kk], a2 = tr[136 + kk], a3 = tr[204 + kk];
        float4 w1 = *(const float4*)(Wpx + kk * 128 + cg * 4);
        float4 w2 = *(const float4*)(Wpx + kk * 128 + 64 + cg * 4);
        acc1[0][0] += a0 * w1.x; acc1[0][1] += a0 * w1.y; acc1[0][2] += a0 * w1.z; acc1[0][3] += a0 * w1.w;
        acc1[1][0] += a1 * w1.x; acc1[1][1] += a1 * w1.y; acc1[1][2] += a1 * w1.z; acc1[1][3] += a1 * w1.w;
        acc1[2][0] += a2 * w1.x; acc1[2][1] += a2 * w1.y; acc1[2][2] += a2 * w1.z; acc1[2][3] += a2 * w1.w;
        acc1[3][0] += a3 * w1.x; acc1[3][1] += a3 * w1.y; acc1[3][2] += a3 * w1.z; acc1[3][3] += a3 * w1.w;
        acc2[0][0] += a0 * w2.x; acc2[0][1] += a0 * w2.y; acc2[0][2] += a0 * w2.z; acc2[0][3] += a0 * w2.w;
        acc2[1][0] += a1 * w2.x; acc2[1][1] += a1 * w2.y; acc2[1][2] += a1 * w2.z; acc2[1][3] += a1 * w2.w;
        acc2[2][0] += a2 * w2.x; acc2[2][1] += a2 * w2.y; acc2[2][2] += a2 * w2.z; acc2[2][3] += a2 * w2.w;
        acc2[3][0] += a3 * w2.x; acc2[3][1] += a3 * w2.y; acc2[3][2] += a3 * w2.z; acc2[3][3] += a3 * w2.w;
    }
    float4 b1 = *(const float4*)(b_px + cg * 4);
    float4 b2 = *(const float4*)(b_px + 64 + cg * 4);
    #pragma unroll
    for (int i = 0; i < 4; i++) {
        int r = row0 + rg * 4 + i;
        u32* d1 = (u32*)(t1 + (size_t)r * 64 + cg * 4);
        d1[0] = pack2(acc1[i][0] + b1.x, acc1[i][1] + b1.y);
        d1[1] = pack2(acc1[i][2] + b1.z, acc1[i][3] + b1.w);
        u32* d2 = (u32*)(t2 + (size_t)r * 64 + cg * 4);
        d2[0] = pack2(acc2[i][0] + b2.x, acc2[i][1] + b2.y);
        d2[1] = pack2(acc2[i][2] + b2.z, acc2[i][3] + b2.w);
    }
}

// ---------- 5. conv + gelu*t2 @ W_pxx + b_pxx + sh -> sh2 (in-place buf_sh) ----------
__global__ __launch_bounds__(256) void k_convpxx(const u16* __restrict__ t1,
                                                 const u16* __restrict__ t2,
                                                 const float* __restrict__ conv_sh,
                                                 const float* __restrict__ W_pxx,
                                                 const float* __restrict__ b_pxx,
                                                 float* __restrict__ buf_sh) {
    __shared__ float Us[64 * 68];
    __shared__ float Wx[4096];
    int row0 = blockIdx.x * 64;
    int tid = threadIdx.x, w = tid >> 6, lane = tid & 63;
    #pragma unroll
    for (int j = 0; j < 4; j++) {
        int e4 = tid + j * 256;
        *(float4*)(Wx + e4 * 4) = *(const float4*)(W_pxx + e4 * 4);
    }
    float c0 = conv_sh[lane * 9 + 0], c1 = conv_sh[lane * 9 + 1], c2 = conv_sh[lane * 9 + 2];
    float c3 = conv_sh[lane * 9 + 3], c4 = conv_sh[lane * 9 + 4], c5 = conv_sh[lane * 9 + 5];
    float c6 = conv_sh[lane * 9 + 6], c7 = conv_sh[lane * 9 + 7], c8 = conv_sh[lane * 9 + 8];
    for (int i = 0; i < 16; i++) {
        int l = i * 4 + w;
        int grow = row0 + l;
        int pix = grow & 255, ii = pix >> 4, jj = pix & 15;
        const u16* p = t1 + (size_t)grow * 64 + lane;
        float c = c4 * bf2f(p[0]);
        if (ii > 0) {
            c += c1 * bf2f(p[-1024]);
            if (jj > 0)  c += c0 * bf2f(p[-1024 - 64]);
            if (jj < 15) c += c2 * bf2f(p[-1024 + 64]);
        }
        if (jj > 0)  c += c3 * bf2f(p[-64]);
        if (jj < 15) c += c5 * bf2f(p[64]);
        if (ii < 15) {
            c += c7 * bf2f(p[1024]);
            if (jj > 0)  c += c6 * bf2f(p[1024 - 64]);
            if (jj < 15) c += c8 * bf2f(p[1024 + 64]);
        }
        Us[l * 68 + lane] = gelu_f(c) * bf2f(t2[(size_t)grow * 64 + lane]);
    }
    __syncthreads();
    int rg = tid >> 4, cg = tid & 15;
    float acc[4][4] = {};
    const float* ur = Us + rg * 4 * 68;
    #pragma unroll 8
    for (int kk = 0; kk < 64; kk++) {
        float a0 = ur[kk], a1 = ur[68 + kk], a2 = ur[136 + kk], a3 = ur[204 + kk];
        float4 wv = *(const float4*)(Wx + kk * 64 + cg * 4);
        acc[0][0] += a0 * wv.x; acc[0][1] += a0 * wv.y; acc[0][2] += a0 * wv.z; acc[0][3] += a0 * wv.w;
        acc[1][0] += a1 * wv.x; acc[1][1] += a1 * wv.y; acc[1][2] += a1 * wv.z; acc[1][3] += a1 * wv.w;
        acc[2][0] += a2 * wv.x; acc[2][1] += a2 * wv.y; acc[2][2] += a2 * wv.z; acc[2][3] += a2 * wv.w;
        acc[3][0] += a3 * wv.x; acc[3][1] += a3 * wv.y; acc[3][2] += a3 * wv.z; acc[3][3] += a3 * wv.w;
    }
    float4 bp = *(const float4*)(b_pxx + cg * 4);
    #pragma unroll
    for (int i = 0; i < 4; i++) {
        int r = row0 + rg * 4 + i;
        float4 shv = *(const float4*)(buf_sh + (size_t)r * 64 + cg * 4);
        float4 o = make_float4(acc[i][0] + bp.x + shv.x, acc[i][1] + bp.y + shv.y,
                               acc[i][2] + bp.z + shv.z, acc[i][3] + bp.w + shv.w);
        *(float4*)(buf_sh + (size_t)r * 64 + cg * 4) = o;
    }
}

// ---------- 6. final: dte_tok + rgb GEMM + epilogue chain -> out (f32) ----------
__global__ __launch_bounds__(256) void k_final(const float* __restrict__ x,
                                               const float* __restrict__ W_rgb,
                                               const float* __restrict__ b_rgb,
                                               const u16* __restrict__ buf_y,
                                               const float* __restrict__ buf_sh,
                                               const float* __restrict__ W_dte,
                                               const float* __restrict__ b_dte,
                                               const float* __restrict__ W_dteall,
                                               const float* __restrict__ b_dteall,
                                               const float* __restrict__ W_fx,
                                               const float* __restrict__ b_fx,
                                               const float* __restrict__ W_fmod,
                                               const float* __restrict__ b_fmod,
                                               const float* __restrict__ W_fxx,
                                               const float* __restrict__ b_fxx,
                                               float* __restrict__ out) {
    __shared__ __align__(16) char pool[52224];
    float* P0 = (float*)pool;            // As / Ys / Gm / Ps   (stride 68)
    float* P1 = (float*)(pool + 17408);  // Ws / Ss / Ga        (stride 68)
    float* RS = (float*)(pool + 34816);  // rgb                 (stride 64)
    int row0 = blockIdx.x * 64;
    int tid = threadIdx.x, rg = tid >> 4, cg = tid & 15;

    // --- rgb GEMM: K=768 ---
    float accR[4][4] = {};
    for (int kc = 0; kc < 12; kc++) {
        __syncthreads();
        #pragma unroll
        for (int j = 0; j < 4; j++) {
            int e4 = tid + j * 256;
            int r = e4 >> 4, kq = e4 & 15;
            *(float4*)(P0 + r * 68 + kq * 4) =
                *(const float4*)(x + (size_t)(row0 + r) * 768 + kc * 64 + kq * 4);
        }
        #pragma unroll
        for (int j = 0; j < 4; j++) {
            int e4 = tid + j * 256;
            int k = e4 >> 4, hq = e4 & 15;
            *(float4*)(P1 + k * 68 + hq * 4) =
                *(const float4*)(W_rgb + (size_t)(kc * 64 + k) * 64 + hq * 4);
        }
        __syncthreads();
        const float* ar = P0 + rg * 4 * 68;
        #pragma unroll 8
        for (int kk = 0; kk < 64; kk++) {
            float a0 = ar[kk], a1 = ar[68 + kk], a2 = ar[136 + kk], a3 = ar[204 + kk];
            float4 wv = *(const float4*)(P1 + kk * 68 + cg * 4);
            accR[0][0] += a0 * wv.x; accR[0][1] += a0 * wv.y; accR[0][2] += a0 * wv.z; accR[0][3] += a0 * wv.w;
            accR[1][0] += a1 * wv.x; accR[1][1] += a1 * wv.y; accR[1][2] += a1 * wv.z; accR[1][3] += a1 * wv.w;
            accR[2][0] += a2 * wv.x; accR[2][1] += a2 * wv.y; accR[2][2] += a2 * wv.z; accR[2][3] += a2 * wv.w;
            accR[3][0] += a3 * wv.x; accR[3][1] += a3 * wv.y; accR[3][2] += a3 * wv.z; accR[3][3] += a3 * wv.w;
        }
    }
    __syncthreads();
    {
        float4 br = *(const float4*)(b_rgb + cg * 4);
        #pragma unroll
        for (int i = 0; i < 4; i++) {
            *(float4*)(RS + (rg * 4 + i) * 64 + cg * 4) =
                make_float4(accR[i][0] + br.x, accR[i][1] + br.y, accR[i][2] + br.z, accR[i][3] + br.w);
        }
    }
    __syncthreads();

    // --- stage Ys (y) and Ss (sh2) ---
    #pragma unroll
    for (int j = 0; j < 16; j++) {
        int e = tid + j * 256;
        int r = e >> 6, c = e & 63;
        P0[r * 68 + c] = bf2f(buf_y[(size_t)(row0 + r) * 64 + c]);
        P1[r * 68 + c] = buf_sh[(size_t)(row0 + r) * 64 + c];
    }
    __syncthreads();

    // --- micro: dte_tok = y@W_dte + sh2@W_dteall ---
    float accD[4][4] = {};
    {
        const float* yr = P0 + rg * 4 * 68;
        const float* sr = P1 + rg * 4 * 68;
        #pragma unroll 4
        for (int kk = 0; kk < 64; kk++) {
            float y0 = yr[kk], y1 = yr[68 + kk], y2 = yr[136 + kk], y3 = yr[204 + kk];
            float s0 = sr[kk], s1 = sr[68 + kk], s2 = sr[136 + kk], s3 = sr[204 + kk];
            float4 w1 = *(const float4*)(W_dte + kk * 64 + cg * 4);
            float4 w2 = *(const float4*)(W_dteall + kk * 64 + cg * 4);
            accD[0][0] += y0 * w1.x + s0 * w2.x; accD[0][1] += y0 * w1.y + s0 * w2.y;
            accD[0][2] += y0 * w1.z + s0 * w2.z; accD[0][3] += y0 * w1.w + s0 * w2.w;
            accD[1][0] += y1 * w1.x + s1 * w2.x; accD[1][1] += y1 * w1.y + s1 * w2.y;
            accD[1][2] += y1 * w1.z + s1 * w2.z; accD[1][3] += y1 * w1.w + s1 * w2.w;
            accD[2][0] += y2 * w1.x + s2 * w2.x; accD[2][1] += y2 * w1.y + s2 * w2.y;
            accD[2][2] += y2 * w1.z + s2 * w2.z; accD[2][3] += y2 * w1.w + s2 * w2.w;
            accD[3][0] += y3 * w1.x + s3 * w2.x; accD[3][1] += y3 * w1.y + s3 * w2.y;
            accD[3][2] += y3 * w1.z + s3 * w2.z; accD[3][3] += y3 * w1.w + s3 * w2.w;
        }
    }
    __syncthreads();
    // --- Gm = gelu(dte_tok) -> P0; Ga = gelu(rgb) -> P1 ---
    {
        float4 bd1 = *(const float4*)(b_dte + cg * 4);
        float4 bd2 = *(const float4*)(b_dteall + cg * 4);
        float bd[4] = { bd1.x + bd2.x, bd1.y + bd2.y, bd1.z + bd2.z, bd1.w + bd2.w };
        #pragma unroll
        for (int i = 0; i < 4; i++) {
            int r = rg * 4 + i;
            #pragma unroll
            for (int j = 0; j < 4; j++) {
                P0[r * 68 + cg * 4 + j] = gelu_f(accD[i][j] + bd[j]);
                P1[r * 68 + cg * 4 + j] = gelu_f(RS[r * 64 + cg * 4 + j]);
            }
        }
    }
    __syncthreads();

    // --- micro: a = Ga@W_fx, m = Gm@W_fmod ---
    float accA[4][4] = {}, accM[4][4] = {};
    {
        const float* gm = P0 + rg * 4 * 68;
        const float* ga = P1 + rg * 4 * 68;
        #pragma unroll 4
        for (int kk = 0; kk < 64; kk++) {
            float m0 = gm[kk], m1 = gm[68 + kk], m2 = gm[136 + kk], m3 = gm[204 + kk];
            float a0 = ga[kk], a1 = ga[68 + kk], a2 = ga[136 + kk], a3 = ga[204 + kk];
            float4 wa = *(const float4*)(W_fx + kk * 64 + cg * 4);
            float4 wm = *(const float4*)(W_fmod + kk * 64 + cg * 4);
            accA[0][0] += a0 * wa.x; accA[0][1] += a0 * wa.y; accA[0][2] += a0 * wa.z; accA[0][3] += a0 * wa.w;
            accA[1][0] += a1 * wa.x; accA[1][1] += a1 * wa.y; accA[1][2] += a1 * wa.z; accA[1][3] += a1 * wa.w;
            accA[2][0] += a2 * wa.x; accA[2][1] += a2 * wa.y; accA[2][2] += a2 * wa.z; accA[2][3] += a2 * wa.w;
            accA[3][0] += a3 * wa.x; accA[3][1] += a3 * wa.y; accA[3][2] += a3 * wa.z; accA[3][3] += a3 * wa.w;
            accM[0][0] += m0 * wm.x; accM[0][1] += m0 * wm.y; accM[0][2] += m0 * wm.z; accM[0][3] += m0 * wm.w;
            accM[1][0] += m1 * wm.x; accM[1][1] += m1 * wm.y; accM[1][2] += m1 * wm.z; accM[1][3] += m1 * wm.w;
            accM[2][0] += m2 * wm.x; accM[2][1] += m2 * wm.y; accM[2][2] += m2 * wm.z; accM[2][3] += m2 * wm.w;
            accM[3][0] += m3 * wm.x; accM[3][1] += m3 * wm.y; accM[3][2] += m3 * wm.z; accM[3][3] += m3 * wm.w;
        }
    }
    __syncthreads();
    // --- Ps = gelu(m)*a -> P0 ---
    {
        float4 bfx4 = *(const float4*)(b_fx + cg * 4);
        float4 bfm4 = *(const float4*)(b_fmod + cg * 4);
        float bx[4] = { bfx4.x, bfx4.y, bfx4.z, bfx4.w };
        float bm[4] = { bfm4.x, bfm4.y, bfm4.z, bfm4.w };
        #pragma unroll
        for (int i = 0; i < 4; i++) {
            int r = rg * 4 + i;
            #pragma unroll
            for (int j = 0; j < 4; j++) {
                float a = accA[i][j] + bx[j];
                float m = accM[i][j] + bm[j];
                P0[r * 68 + cg * 4 + j] = gelu_f(m) * a;
            }
        }
    }
    __syncthreads();

    // --- micro: out = Ps@W_fxx + b_fxx + rgb ---
    float accO[4][4] = {};
    {
        const float* pr = P0 + rg * 4 * 68;
        #pragma unroll 8
        for (int kk = 0; kk < 64; kk++) {
            float p0 = pr[kk], p1 = pr[68 + kk], p2 = pr[136 + kk], p3 = pr[204 + kk];
            float4 wv = *(const float4*)(W_fxx + kk * 64 + cg * 4);
            accO[0][0] += p0 * wv.x; accO[0][1] += p0 * wv.y; accO[0][2] += p0 * wv.z; accO[0][3] += p0 * wv.w;
            accO[1][0] += p1 * wv.x; accO[1][1] += p1 * wv.y; accO[1][2] += p1 * wv.z; accO[1][3] += p1 * wv.w;
            accO[2][0] += p2 * wv.x; accO[2][1] += p2 * wv.y; accO[2][2] += p2 * wv.z; accO[2][3] += p2 * wv.w;
            accO[3][0] += p3 * wv.x; accO[3][1] += p3 * wv.y; accO[3][2] += p3 * wv.z; accO[3][3] += p3 * wv.w;
        }
    }
    {
        float4 bo = *(const float4*)(b_fxx + cg * 4);
        #pragma unroll
        for (int i = 0; i < 4; i++) {
            int r = rg * 4 + i;
            float4 o = make_float4(accO[i][0] + bo.x + RS[r * 64 + cg * 4 + 0],
                                   accO[i][1] + bo.y + RS[r * 64 + cg * 4 + 1],
                                   accO[i][2] + bo.z + RS[r * 64 + cg * 4 + 2],
                                   accO[i][3] + bo.w + RS[r * 64 + cg * 4 + 3]);
            *(float4*)(out + (size_t)(row0 + r) * 64 + cg * 4) = o;
        }
    }
}

extern "C" void kernel_launch(void* const* d_in, const int* in_sizes, int n_in,
                              void* d_out, int out_size, void* d_ws, size_t ws_size,
                              hipStream_t stream) {
    const float* x       = (const float*)d_in[0];
    const float* dte     = (const float*)d_in[1];
    const float* w_gate  = (const float*)d_in[2];
    const float* W_exp   = (const float*)d_in[3];
    const float* b_exp   = (const float*)d_in[4];
    const float* W_sh    = (const float*)d_in[5];
    const float* b_sh    = (const float*)d_in[6];
    const float* ln_g    = (const float*)d_in[7];
    const float* ln_b    = (const float*)d_in[8];
    const float* W_px    = (const float*)d_in[9];
    const float* b_px    = (const float*)d_in[10];
    const float* conv_sh = (const float*)d_in[11];
    const float* W_pxx   = (const float*)d_in[12];
    const float* b_pxx   = (const float*)d_in[13];
    const float* W_dte   = (const float*)d_in[14];
    const float* b_dte   = (const float*)d_in[15];
    const float* W_dteall= (const float*)d_in[16];
    const float* b_dteall= (const float*)d_in[17];
    const float* W_rgb   = (const float*)d_in[18];
    const float* b_rgb   = (const float*)d_in[19];
    const float* W_fx    = (const float*)d_in[20];
    const float* b_fx    = (const float*)d_in[21];
    const float* W_fmod  = (const float*)d_in[22];
    const float* b_fmod  = (const float*)d_in[23];
    const float* W_fxx   = (const float*)d_in[24];
    const float* b_fxx   = (const float*)d_in[25];

    float* out = (float*)d_out;     // [0,1048576) plane + loss at [1048576]

    // workspace: ~10.5 MB
    float* wsf   = (float*)d_ws;
    float* gates = wsf;                         // 512
    int*   topi  = (int*)(wsf + 512);           // 128
    float* topg  = wsf + 640;                   // 128
    float* bias_y= wsf + 768;                   // 4096
    float* buf_sh= wsf + 8192;                  // 1048576 f32 (sh -> sh2)
    u16*   buf_y = (u16*)(wsf + 8192 + 1048576);            // 1048576 bf16 (y -> read by final)
    u16*   t1    = (u16*)(wsf + 8192 + 1048576 + 524288);   // 1048576 bf16
    u16*   t2    = (u16*)(wsf + 8192 + 1048576 + 524288*2); // 1048576 bf16

    hipLaunchKernelGGL(k_gates, dim3(64), dim3(256), 0, stream,
                       dte, w_gate, b_exp, gates, topi, topg, bias_y);
    hipLaunchKernelGGL(k_loss, dim3(1), dim3(64), 0, stream, gates, out + 1048576);
    hipLaunchKernelGGL(k_gemm_sh_y, dim3(512), dim3(256), 0, stream,
                       dte, W_sh, b_sh, W_exp, topi, topg, bias_y, buf_sh, buf_y);
    hipLaunchKernelGGL(k_lnpx, dim3(256), dim3(256), 0, stream,
                       buf_sh, ln_g, ln_b, W_px, b_px, t1, t2);
    hipLaunchKernelGGL(k_convpxx, dim3(256), dim3(256), 0, stream,
                       t1, t2, conv_sh, W_pxx, b_pxx, buf_sh);
    hipLaunchKernelGGL(k_final, dim3(256), dim3(256), 0, stream,
                       x, W_rgb, b_rgb, buf_y, buf_sh, W_dte, b_dte, W_dteall, b_dteall,
                       W_fx, b_fx, W_fmod, b_fmod, W_fxx, b_fxx, out);

    (void)in_sizes; (void)n_in; (void)out_size; (void)ws_size;
}

// Round 7
// 292.770 us; speedup vs baseline: 4.8431x; 1.2424x over previous
//
#include <hip/hip_runtime.h>
#include <math.h>

typedef unsigned short u16;
typedef unsigned int u32;

// B=64, L=256, DIN=768, H=64, E=8, K=2, S=16; BL=16384. All inputs f32, output f32.

__device__ __forceinline__ float bf2f(u16 u) {
    union { u32 i; float f; } x; x.i = ((u32)u) << 16; return x.f;
}
__device__ __forceinline__ u16 f2bf(float f) {
    union { float f; u32 i; } x; x.f = f;
    u32 i = x.i;
    return (u16)((i + 0x7fffu + ((i >> 16) & 1u)) >> 16);
}
__device__ __forceinline__ u32 pack2(float a, float b) {
    return (u32)f2bf(a) | ((u32)f2bf(b) << 16);
}
__device__ __forceinline__ float wsum(float v) {
    #pragma unroll
    for (int o = 1; o < 64; o <<= 1) v += __shfl_xor(v, o, 64);
    return v;
}
__device__ __forceinline__ float gelu_f(float x) {
    return 0.5f * x * (1.0f + erff(x * 0.70710678118654752440f));
}

// ---------- 1a. partial gating: block p handles rows [p*64, p*64+64) of batch p>>2 ----------
__global__ __launch_bounds__(256) void k_gate_part(const float* __restrict__ dte,
                                                   const float* __restrict__ w_gate,
                                                   float* __restrict__ partial) {
    __shared__ float dmeanS[64];
    int p = blockIdx.x, tid = threadIdx.x, w = tid >> 6, lane = tid & 63;
    // row sums: 4 waves x 16 rows
    for (int i = 0; i < 16; i++) {
        int l = w * 16 + i;
        const float* pr = dte + ((size_t)p * 64 + l) * 768;
        float s = 0.f;
        #pragma unroll
        for (int j = 0; j < 12; j++) s += pr[j * 64 + lane];
        s = wsum(s);
        if (lane == 0) dmeanS[l] = s * (1.f / 768.f);
    }
    __syncthreads();
    if (w == 0) {
        float dm = dmeanS[lane];
        int wl = (p & 3) * 64 + lane;   // w_gate row (position within batch)
        #pragma unroll
        for (int e = 0; e < 8; e++) {
            float s = wsum(dm * w_gate[wl * 8 + e]);
            if (lane == 0) partial[p * 8 + e] = s;
        }
    }
}

// ---------- 1b. finalize gates: top2, softmax, bias_y, topi/topg, loss ----------
__global__ __launch_bounds__(256) void k_gate_fin(const float* __restrict__ partial,
                                                  const float* __restrict__ b_exp,
                                                  int* __restrict__ topi,
                                                  float* __restrict__ topg,
                                                  float* __restrict__ bias_y,
                                                  float* __restrict__ loss_out) {
    __shared__ float gS[64 * 8];
    __shared__ int i0S[64], i1S[64];
    __shared__ float g0S[64], g1S[64];
    int tid = threadIdx.x;
    if (tid < 64) {
        float lg[8];
        #pragma unroll
        for (int e = 0; e < 8; e++)
            lg[e] = partial[(tid * 4 + 0) * 8 + e] + partial[(tid * 4 + 1) * 8 + e] +
                    partial[(tid * 4 + 2) * 8 + e] + partial[(tid * 4 + 3) * 8 + e];
        int i0 = 0; float v0 = lg[0];
        #pragma unroll
        for (int e = 1; e < 8; e++) if (lg[e] > v0) { v0 = lg[e]; i0 = e; }
        int i1 = -1; float v1 = -1e30f;
        #pragma unroll
        for (int e = 0; e < 8; e++) if (e != i0 && lg[e] > v1) { v1 = lg[e]; i1 = e; }
        if (i1 < 0) i1 = (i0 + 1) & 7;
        float e2 = expf(v1 - v0);
        float g0 = 1.f / (1.f + e2);
        float g1 = e2 / (1.f + e2);
        #pragma unroll
        for (int e = 0; e < 8; e++) gS[tid * 8 + e] = 0.f;
        gS[tid * 8 + i0] = g0;
        gS[tid * 8 + i1] = g1;
        i0S[tid] = i0; i1S[tid] = i1; g0S[tid] = g0; g1S[tid] = g1;
        topi[tid * 2] = i0; topi[tid * 2 + 1] = i1;
        topg[tid * 2] = g0; topg[tid * 2 + 1] = g1;
    }
    __syncthreads();
    for (int idx = tid; idx < 4096; idx += 256) {
        int b = idx >> 6, h = idx & 63;
        bias_y[idx] = g0S[b] * b_exp[i0S[b] * 64 + h] + g1S[b] * b_exp[i1S[b] * 64 + h];
    }
    if (tid < 64) {
        float g[8];
        #pragma unroll
        for (int e = 0; e < 8; e++) g[e] = gS[tid * 8 + e];
        float imp[8], ld[8];
        #pragma unroll
        for (int e = 0; e < 8; e++) {
            imp[e] = wsum(g[e]);
            ld[e]  = wsum(g[e] > 0.f ? 1.f : 0.f);
        }
        if (tid == 0) {
            float l = 0.f;
            {
                float s = 0.f;
                #pragma unroll
                for (int e = 0; e < 8; e++) s += imp[e];
                float mn = s / 8.f, v = 0.f;
                #pragma unroll
                for (int e = 0; e < 8; e++) { float d = imp[e] - mn; v += d * d; }
                l += (v / 7.f) / (mn * mn + 1e-10f);
            }
            {
                float s = 0.f;
                #pragma unroll
                for (int e = 0; e < 8; e++) s += ld[e];
                float mn = s / 8.f, v = 0.f;
                #pragma unroll
                for (int e = 0; e < 8; e++) { float d = ld[e] - mn; v += d * d; }
                l += (v / 7.f) / (mn * mn + 1e-10f);
            }
            loss_out[0] = 0.01f * l;
        }
    }
}

// ---------- 2. all three K=768 GEMMs: kind0 -> sh (f32 ws), kind1 -> y (bf16 ws),
//             kind2 -> rgb (f32 into the d_out plane; k_tail reads then overwrites) ----------
__global__ __launch_bounds__(256) void k_gemm3(const float* __restrict__ dte,
                                               const float* __restrict__ x,
                                               const float* __restrict__ W_sh,
                                               const float* __restrict__ b_sh,
                                               const float* __restrict__ W_exp,
                                               const int* __restrict__ topi,
                                               const float* __restrict__ topg,
                                               const float* __restrict__ bias_y,
                                               const float* __restrict__ W_rgb,
                                               const float* __restrict__ b_rgb,
                                               float* __restrict__ buf_sh,
                                               u16* __restrict__ buf_y,
                                               float* __restrict__ out_rgb) {
    __shared__ float As[64 * 68];
    __shared__ float Ws[64 * 68];
    int bid = blockIdx.x;
    int kind = bid >> 8;                    // 0=sh, 1=y, 2=rgb
    int row0 = (bid & 255) * 64;
    int b = row0 >> 8;
    int tid = threadIdx.x, rg = tid >> 4, cg = tid & 15;
    const float* A = (kind == 2) ? x : dte;
    const float* W0 = (kind == 2) ? W_rgb : W_sh;
    const float* W1 = W0;
    float g0 = 0.f, g1 = 0.f;
    if (kind == 1) {
        W0 = W_exp + (size_t)topi[2 * b] * 49152;
        W1 = W_exp + (size_t)topi[2 * b + 1] * 49152;
        g0 = topg[2 * b]; g1 = topg[2 * b + 1];
    }
    float acc[4][4] = {};
    for (int kc = 0; kc < 12; kc++) {
        __syncthreads();
        #pragma unroll
        for (int j = 0; j < 4; j++) {
            int e4 = tid + j * 256;
            int r = e4 >> 4, kq = e4 & 15;
            *(float4*)(As + r * 68 + kq * 4) =
                *(const float4*)(A + (size_t)(row0 + r) * 768 + kc * 64 + kq * 4);
        }
        #pragma unroll
        for (int j = 0; j < 4; j++) {
            int e4 = tid + j * 256;
            int k = e4 >> 4, hq = e4 & 15;
            size_t off = (size_t)(kc * 64 + k) * 64 + hq * 4;
            float4 wv;
            if (kind == 1) {
                float4 a = *(const float4*)(W0 + off);
                float4 c = *(const float4*)(W1 + off);
                wv.x = g0 * a.x + g1 * c.x; wv.y = g0 * a.y + g1 * c.y;
                wv.z = g0 * a.z + g1 * c.z; wv.w = g0 * a.w + g1 * c.w;
            } else {
                wv = *(const float4*)(W0 + off);
            }
            *(float4*)(Ws + k * 68 + hq * 4) = wv;
        }
        __syncthreads();
        const float* ar = As + rg * 4 * 68;
        #pragma unroll 8
        for (int kk = 0; kk < 64; kk++) {
            float a0 = ar[kk], a1 = ar[68 + kk], a2 = ar[136 + kk], a3 = ar[204 + kk];
            float4 wv = *(const float4*)(Ws + kk * 68 + cg * 4);
            acc[0][0] += a0 * wv.x; acc[0][1] += a0 * wv.y; acc[0][2] += a0 * wv.z; acc[0][3] += a0 * wv.w;
            acc[1][0] += a1 * wv.x; acc[1][1] += a1 * wv.y; acc[1][2] += a1 * wv.z; acc[1][3] += a1 * wv.w;
            acc[2][0] += a2 * wv.x; acc[2][1] += a2 * wv.y; acc[2][2] += a2 * wv.z; acc[2][3] += a2 * wv.w;
            acc[3][0] += a3 * wv.x; acc[3][1] += a3 * wv.y; acc[3][2] += a3 * wv.z; acc[3][3] += a3 * wv.w;
        }
    }
    if (kind == 0) {
        float4 bs = *(const float4*)(b_sh + cg * 4);
        #pragma unroll
        for (int i = 0; i < 4; i++) {
            int r = row0 + rg * 4 + i;
            *(float4*)(buf_sh + (size_t)r * 64 + cg * 4) =
                make_float4(acc[i][0] + bs.x, acc[i][1] + bs.y, acc[i][2] + bs.z, acc[i][3] + bs.w);
        }
    } else if (kind == 1) {
        float4 by = *(const float4*)(bias_y + b * 64 + cg * 4);
        #pragma unroll
        for (int i = 0; i < 4; i++) {
            int r = row0 + rg * 4 + i;
            u32* dst = (u32*)(buf_y + (size_t)r * 64 + cg * 4);
            dst[0] = pack2(acc[i][0] + by.x, acc[i][1] + by.y);
            dst[1] = pack2(acc[i][2] + by.z, acc[i][3] + by.w);
        }
    } else {
        float4 br = *(const float4*)(b_rgb + cg * 4);
        #pragma unroll
        for (int i = 0; i < 4; i++) {
            int r = row0 + rg * 4 + i;
            *(float4*)(out_rgb + (size_t)r * 64 + cg * 4) =
                make_float4(acc[i][0] + br.x, acc[i][1] + br.y, acc[i][2] + br.z, acc[i][3] + br.w);
        }
    }
}

// ---------- 3. LN + W_px -> t1, t2 (bf16); 32-row tiles, grid 512 ----------
__global__ __launch_bounds__(256) void k_lnpx(const float* __restrict__ buf_sh,
                                              const float* __restrict__ ln_g,
                                              const float* __restrict__ ln_b,
                                              const float* __restrict__ W_px,
                                              const float* __restrict__ b_px,
                                              u16* __restrict__ t1, u16* __restrict__ t2) {
    __shared__ float T[32 * 68];
    __shared__ float Wpx[8192];
    int r0 = blockIdx.x * 32;
    int tid = threadIdx.x, w = tid >> 6, lane = tid & 63;
    #pragma unroll
    for (int j = 0; j < 8; j++) {
        int e4 = tid + j * 256;
        *(float4*)(Wpx + e4 * 4) = *(const float4*)(W_px + e4 * 4);
    }
    float lnG = ln_g[lane], lnB = ln_b[lane];
    for (int i = 0; i < 8; i++) {
        int l = w * 8 + i;
        float v = buf_sh[(size_t)(r0 + l) * 64 + lane];
        float mean = wsum(v) * (1.f / 64.f);
        float d = v - mean;
        float var = wsum(d * d) * (1.f / 64.f);
        T[l * 68 + lane] = d * rsqrtf(var + 1e-6f) * lnG + lnB;
    }
    __syncthreads();
    int rg = tid >> 4, cg = tid & 15;
    float acc1[2][4] = {}, acc2[2][4] = {};
    const float* tr = T + rg * 2 * 68;
    #pragma unroll 4
    for (int kk = 0; kk < 64; kk++) {
        float a0 = tr[kk], a1 = tr[68 + kk];
        float4 w1 = *(const float4*)(Wpx + kk * 128 + cg * 4);
        float4 w2 = *(const float4*)(Wpx + kk * 128 + 64 + cg * 4);
        acc1[0][0] += a0 * w1.x; acc1[0][1] += a0 * w1.y; acc1[0][2] += a0 * w1.z; acc1[0][3] += a0 * w1.w;
        acc1[1][0] += a1 * w1.x; acc1[1][1] += a1 * w1.y; acc1[1][2] += a1 * w1.z; acc1[1][3] += a1 * w1.w;
        acc2[0][0] += a0 * w2.x; acc2[0][1] += a0 * w2.y; acc2[0][2] += a0 * w2.z; acc2[0][3] += a0 * w2.w;
        acc2[1][0] += a1 * w2.x; acc2[1][1] += a1 * w2.y; acc2[1][2] += a1 * w2.z; acc2[1][3] += a1 * w2.w;
    }
    float4 b1 = *(const float4*)(b_px + cg * 4);
    float4 b2 = *(const float4*)(b_px + 64 + cg * 4);
    #pragma unroll
    for (int i = 0; i < 2; i++) {
        int r = r0 + rg * 2 + i;
        u32* d1 = (u32*)(t1 + (size_t)r * 64 + cg * 4);
        d1[0] = pack2(acc1[i][0] + b1.x, acc1[i][1] + b1.y);
        d1[1] = pack2(acc1[i][2] + b1.z, acc1[i][3] + b1.w);
        u32* d2 = (u32*)(t2 + (size_t)r * 64 + cg * 4);
        d2[0] = pack2(acc2[i][0] + b2.x, acc2[i][1] + b2.y);
        d2[1] = pack2(acc2[i][2] + b2.z, acc2[i][3] + b2.w);
    }
}

// ---------- 4. tail: conv+pxx+residual -> dtetok -> fx/fmod -> fxx + rgb residual.
//             32-row tiles, grid 512. rgb lives in the d_out plane (read then overwrite). ----------
__global__ __launch_bounds__(256) void k_tail(const u16* __restrict__ t1,
                                              const u16* __restrict__ t2,
                                              const float* __restrict__ conv_sh,
                                              const float* __restrict__ W_pxx,
                                              const float* __restrict__ b_pxx,
                                              const float* __restrict__ buf_sh,
                                              const u16* __restrict__ buf_y,
                                              const float* __restrict__ W_dte,
                                              const float* __restrict__ b_dte,
                                              const float* __restrict__ W_dteall,
                                              const float* __restrict__ b_dteall,
                                              const float* __restrict__ W_fx,
                                              const float* __restrict__ b_fx,
                                              const float* __restrict__ W_fmod,
                                              const float* __restrict__ b_fmod,
                                              const float* __restrict__ W_fxx,
                                              const float* __restrict__ b_fxx,
                                              float* __restrict__ out) {
    __shared__ float B0[32 * 68];   // Us -> Ys -> Ps
    __shared__ float B1[32 * 68];   // SS -> Ga
    __shared__ float B2[32 * 68];   // Gm
    __shared__ float RS[32 * 64];   // rgb
    int r0 = blockIdx.x * 32;
    int tid = threadIdx.x, w = tid >> 6, lane = tid & 63;
    int rg = tid >> 4, cg = tid & 15;

    // stage 1: u = gelu(conv(t1)) * t2 -> B0
    {
        float c0 = conv_sh[lane * 9 + 0], c1 = conv_sh[lane * 9 + 1], c2 = conv_sh[lane * 9 + 2];
        float c3 = conv_sh[lane * 9 + 3], c4 = conv_sh[lane * 9 + 4], c5 = conv_sh[lane * 9 + 5];
        float c6 = conv_sh[lane * 9 + 6], c7 = conv_sh[lane * 9 + 7], c8 = conv_sh[lane * 9 + 8];
        for (int i = 0; i < 8; i++) {
            int l = w * 8 + i;
            int gr = r0 + l;
            int pix = gr & 255, ii = pix >> 4, jj = pix & 15;
            const u16* p = t1 + (size_t)gr * 64 + lane;
            float c = c4 * bf2f(p[0]);
            if (ii > 0) {
                c += c1 * bf2f(p[-1024]);
                if (jj > 0)  c += c0 * bf2f(p[-1024 - 64]);
                if (jj < 15) c += c2 * bf2f(p[-1024 + 64]);
            }
            if (jj > 0)  c += c3 * bf2f(p[-64]);
            if (jj < 15) c += c5 * bf2f(p[64]);
            if (ii < 15) {
                c += c7 * bf2f(p[1024]);
                if (jj > 0)  c += c6 * bf2f(p[1024 - 64]);
                if (jj < 15) c += c8 * bf2f(p[1024 + 64]);
            }
            B0[l * 68 + lane] = gelu_f(c) * bf2f(t2[(size_t)gr * 64 + lane]);
        }
    }
    __syncthreads();

    // stage 2: sh2 = B0 @ W_pxx + b_pxx + sh -> B1
    {
        float acc[2][4] = {};
        const float* ur = B0 + rg * 2 * 68;
        #pragma unroll 8
        for (int kk = 0; kk < 64; kk++) {
            float a0 = ur[kk], a1 = ur[68 + kk];
            float4 wv = *(const float4*)(W_pxx + kk * 64 + cg * 4);
            acc[0][0] += a0 * wv.x; acc[0][1] += a0 * wv.y; acc[0][2] += a0 * wv.z; acc[0][3] += a0 * wv.w;
            acc[1][0] += a1 * wv.x; acc[1][1] += a1 * wv.y; acc[1][2] += a1 * wv.z; acc[1][3] += a1 * wv.w;
        }
        float4 bp = *(const float4*)(b_pxx + cg * 4);
        #pragma unroll
        for (int i = 0; i < 2; i++) {
            int lr = rg * 2 + i;
            float4 shv = *(const float4*)(buf_sh + (size_t)(r0 + lr) * 64 + cg * 4);
            *(float4*)(B1 + lr * 68 + cg * 4) =
                make_float4(acc[i][0] + bp.x + shv.x, acc[i][1] + bp.y + shv.y,
                            acc[i][2] + bp.z + shv.z, acc[i][3] + bp.w + shv.w);
        }
    }
    __syncthreads();

    // stage 3: Ys -> B0 (overwrite Us)
    #pragma unroll
    for (int j = 0; j < 8; j++) {
        int e = tid + j * 256;
        int l = e >> 6, c = e & 63;
        B0[l * 68 + c] = bf2f(buf_y[(size_t)(r0 + l) * 64 + c]);
    }
    __syncthreads();

    // stage 4: dte_tok = Ys@W_dte + SS@W_dteall + biases; Gm = gelu -> B2
    {
        float acc[2][4] = {};
        const float* yr = B0 + rg * 2 * 68;
        const float* sr = B1 + rg * 2 * 68;
        #pragma unroll 4
        for (int kk = 0; kk < 64; kk++) {
            float y0 = yr[kk], y1 = yr[68 + kk];
            float s0 = sr[kk], s1 = sr[68 + kk];
            float4 w1 = *(const float4*)(W_dte + kk * 64 + cg * 4);
            float4 w2 = *(const float4*)(W_dteall + kk * 64 + cg * 4);
            acc[0][0] += y0 * w1.x + s0 * w2.x; acc[0][1] += y0 * w1.y + s0 * w2.y;
            acc[0][2] += y0 * w1.z + s0 * w2.z; acc[0][3] += y0 * w1.w + s0 * w2.w;
            acc[1][0] += y1 * w1.x + s1 * w2.x; acc[1][1] += y1 * w1.y + s1 * w2.y;
            acc[1][2] += y1 * w1.z + s1 * w2.z; acc[1][3] += y1 * w1.w + s1 * w2.w;
        }
        float4 bd1 = *(const float4*)(b_dte + cg * 4);
        float4 bd2 = *(const float4*)(b_dteall + cg * 4);
        #pragma unroll
        for (int i = 0; i < 2; i++) {
            int lr = rg * 2 + i;
            *(float4*)(B2 + lr * 68 + cg * 4) =
                make_float4(gelu_f(acc[i][0] + bd1.x + bd2.x), gelu_f(acc[i][1] + bd1.y + bd2.y),
                            gelu_f(acc[i][2] + bd1.z + bd2.z), gelu_f(acc[i][3] + bd1.w + bd2.w));
        }
    }
    __syncthreads();

    // stage 5: rgb from out plane -> RS; Ga = gelu(rgb) -> B1 (overwrite SS)
    #pragma unroll
    for (int j = 0; j < 2; j++) {
        int e4 = tid + j * 256;          // 512 float4 = 2048 floats = 32x64
        int l = e4 >> 4, c4i = e4 & 15;
        float4 rv = *(const float4*)(out + (size_t)(r0 + l) * 64 + c4i * 4);
        *(float4*)(RS + l * 64 + c4i * 4) = rv;
        B1[l * 68 + c4i * 4 + 0] = gelu_f(rv.x);
        B1[l * 68 + c4i * 4 + 1] = gelu_f(rv.y);
        B1[l * 68 + c4i * 4 + 2] = gelu_f(rv.z);
        B1[l * 68 + c4i * 4 + 3] = gelu_f(rv.w);
    }
    __syncthreads();

    // stage 6: a = Ga@W_fx + b_fx; m = Gm@W_fmod + b_fmod; Ps = gelu(m)*a -> B0
    {
        float accA[2][4] = {}, accM[2][4] = {};
        const float* ga = B1 + rg * 2 * 68;
        const float* gm = B2 + rg * 2 * 68;
        #pragma unroll 4
        for (int kk = 0; kk < 64; kk++) {
            float a0 = ga[kk], a1 = ga[68 + kk];
            float m0 = gm[kk], m1 = gm[68 + kk];
            float4 wa = *(const float4*)(W_fx + kk * 64 + cg * 4);
            float4 wm = *(const float4*)(W_fmod + kk * 64 + cg * 4);
            accA[0][0] += a0 * wa.x; accA[0][1] += a0 * wa.y; accA[0][2] += a0 * wa.z; accA[0][3] += a0 * wa.w;
            accA[1][0] += a1 * wa.x; accA[1][1] += a1 * wa.y; accA[1][2] += a1 * wa.z; accA[1][3] += a1 * wa.w;
            accM[0][0] += m0 * wm.x; accM[0][1] += m0 * wm.y; accM[0][2] += m0 * wm.z; accM[0][3] += m0 * wm.w;
            accM[1][0] += m1 * wm.x; accM[1][1] += m1 * wm.y; accM[1][2] += m1 * wm.z; accM[1][3] += m1 * wm.w;
        }
        float4 bx = *(const float4*)(b_fx + cg * 4);
        float4 bm = *(const float4*)(b_fmod + cg * 4);
        #pragma unroll
        for (int i = 0; i < 2; i++) {
            int lr = rg * 2 + i;
            float a0 = accA[i][0] + bx.x, a1 = accA[i][1] + bx.y, a2 = accA[i][2] + bx.z, a3 = accA[i][3] + bx.w;
            float m0 = accM[i][0] + bm.x, m1 = accM[i][1] + bm.y, m2 = accM[i][2] + bm.z, m3 = accM[i][3] + bm.w;
            *(float4*)(B0 + lr * 68 + cg * 4) =
                make_float4(gelu_f(m0) * a0, gelu_f(m1) * a1, gelu_f(m2) * a2, gelu_f(m3) * a3);
        }
    }
    __syncthreads();

    // stage 7: out = Ps@W_fxx + b_fxx + rgb
    {
        float acc[2][4] = {};
        const float* pr = B0 + rg * 2 * 68;
        #pragma unroll 8
        for (int kk = 0; kk < 64; kk++) {
            float p0 = pr[kk], p1 = pr[68 + kk];
            float4 wv = *(const float4*)(W_fxx + kk * 64 + cg * 4);
            acc[0][0] += p0 * wv.x; acc[0][1] += p0 * wv.y; acc[0][2] += p0 * wv.z; acc[0][3] += p0 * wv.w;
            acc[1][0] += p1 * wv.x; acc[1][1] += p1 * wv.y; acc[1][2] += p1 * wv.z; acc[1][3] += p1 * wv.w;
        }
        float4 bo = *(const float4*)(b_fxx + cg * 4);
        #pragma unroll
        for (int i = 0; i < 2; i++) {
            int lr = rg * 2 + i;
            *(float4*)(out + (size_t)(r0 + lr) * 64 + cg * 4) =
                make_float4(acc[i][0] + bo.x + RS[lr * 64 + cg * 4 + 0],
                            acc[i][1] + bo.y + RS[lr * 64 + cg * 4 + 1],
                            acc[i][2] + bo.z + RS[lr * 64 + cg * 4 + 2],
                            acc[i][3] + bo.w + RS[lr * 64 + cg * 4 + 3]);
        }
    }
}

extern "C" void kernel_launch(void* const* d_in, const int* in_sizes, int n_in,
                              void* d_out, int out_size, void* d_ws, size_t ws_size,
                              hipStream_t stream) {
    const float* x       = (const float*)d_in[0];
    const float* dte     = (const float*)d_in[1];
    const float* w_gate  = (const float*)d_in[2];
    const float* W_exp   = (const float*)d_in[3];
    const float* b_exp   = (const float*)d_in[4];
    const float* W_sh    = (const float*)d_in[5];
    const float* b_sh    = (const float*)d_in[6];
    const float* ln_g    = (const float*)d_in[7];
    const float* ln_b    = (const float*)d_in[8];
    const float* W_px    = (const float*)d_in[9];
    const float* b_px    = (const float*)d_in[10];
    const float* conv_sh = (const float*)d_in[11];
    const float* W_pxx   = (const float*)d_in[12];
    const float* b_pxx   = (const float*)d_in[13];
    const float* W_dte   = (const float*)d_in[14];
    const float* b_dte   = (const float*)d_in[15];
    const float* W_dteall= (const float*)d_in[16];
    const float* b_dteall= (const float*)d_in[17];
    const float* W_rgb   = (const float*)d_in[18];
    const float* b_rgb   = (const float*)d_in[19];
    const float* W_fx    = (const float*)d_in[20];
    const float* b_fx    = (const float*)d_in[21];
    const float* W_fmod  = (const float*)d_in[22];
    const float* b_fmod  = (const float*)d_in[23];
    const float* W_fxx   = (const float*)d_in[24];
    const float* b_fxx   = (const float*)d_in[25];

    float* out = (float*)d_out;     // [0,1048576) plane + loss at [1048576]

    // workspace ~10.5 MB (same budget as the passing R6 run)
    float* wsf    = (float*)d_ws;
    float* partial= wsf;                         // 2048
    int*   topi   = (int*)(wsf + 2048);          // 128
    float* topg   = wsf + 2176;                  // 128
    float* bias_y = wsf + 2304;                  // 4096
    float* buf_sh = wsf + 8192;                  // 1048576 f32 (sh -> read by lnpx & tail)
    u16*   buf_y  = (u16*)(wsf + 8192 + 1048576);            // bf16
    u16*   t1     = (u16*)(wsf + 8192 + 1048576 + 524288);   // bf16
    u16*   t2     = (u16*)(wsf + 8192 + 1048576 + 524288*2); // bf16

    hipLaunchKernelGGL(k_gate_part, dim3(256), dim3(256), 0, stream, dte, w_gate, partial);
    hipLaunchKernelGGL(k_gate_fin, dim3(1), dim3(256), 0, stream,
                       partial, b_exp, topi, topg, bias_y, out + 1048576);
    hipLaunchKernelGGL(k_gemm3, dim3(768), dim3(256), 0, stream,
                       dte, x, W_sh, b_sh, W_exp, topi, topg, bias_y, W_rgb, b_rgb,
                       buf_sh, buf_y, out);
    hipLaunchKernelGGL(k_lnpx, dim3(512), dim3(256), 0, stream,
                       buf_sh, ln_g, ln_b, W_px, b_px, t1, t2);
    hipLaunchKernelGGL(k_tail, dim3(512), dim3(256), 0, stream,
                       t1, t2, conv_sh, W_pxx, b_pxx, buf_sh, buf_y,
                       W_dte, b_dte, W_dteall, b_dteall,
                       W_fx, b_fx, W_fmod, b_fmod, W_fxx, b_fxx, out);

    (void)in_sizes; (void)n_in; (void)out_size; (void)ws_size;
}

// Round 8
// 278.740 us; speedup vs baseline: 5.0868x; 1.0503x over previous
//
#include <hip/hip_runtime.h>
#include <math.h>

typedef unsigned short u16;
typedef unsigned int u32;
typedef __attribute__((ext_vector_type(8))) short bf16x8;
typedef __attribute__((ext_vector_type(4))) float f32x4;

// B=64, L=256, DIN=768, H=64, E=8, K=2, S=16; BL=16384. All inputs f32, output f32.

__device__ __forceinline__ float bf2f(u16 u) {
    union { u32 i; float f; } x; x.i = ((u32)u) << 16; return x.f;
}
__device__ __forceinline__ u16 f2bf(float f) {
    union { float f; u32 i; } x; x.f = f;
    u32 i = x.i;
    return (u16)((i + 0x7fffu + ((i >> 16) & 1u)) >> 16);
}
__device__ __forceinline__ u32 pack2(float a, float b) {
    return (u32)f2bf(a) | ((u32)f2bf(b) << 16);
}
__device__ __forceinline__ float wsum(float v) {
    #pragma unroll
    for (int o = 1; o < 64; o <<= 1) v += __shfl_xor(v, o, 64);
    return v;
}
__device__ __forceinline__ float gelu_f(float x) {
    return 0.5f * x * (1.0f + erff(x * 0.70710678118654752440f));
}

// ---------- 1a. partial gating ----------
__global__ __launch_bounds__(256) void k_gate_part(const float* __restrict__ dte,
                                                   const float* __restrict__ w_gate,
                                                   float* __restrict__ partial) {
    __shared__ float dmeanS[64];
    int p = blockIdx.x, tid = threadIdx.x, w = tid >> 6, lane = tid & 63;
    for (int i = 0; i < 16; i++) {
        int l = w * 16 + i;
        const float* pr = dte + ((size_t)p * 64 + l) * 768;
        float s = 0.f;
        #pragma unroll
        for (int j = 0; j < 3; j++) {
            float4 v = *(const float4*)(pr + (lane + j * 64) * 4);
            s += v.x + v.y + v.z + v.w;
        }
        s = wsum(s);
        if (lane == 0) dmeanS[l] = s * (1.f / 768.f);
    }
    __syncthreads();
    if (w == 0) {
        float dm = dmeanS[lane];
        int wl = (p & 3) * 64 + lane;
        #pragma unroll
        for (int e = 0; e < 8; e++) {
            float s = wsum(dm * w_gate[wl * 8 + e]);
            if (lane == 0) partial[p * 8 + e] = s;
        }
    }
}

// ---------- 1b. finalize gates + loss ----------
__global__ __launch_bounds__(256) void k_gate_fin(const float* __restrict__ partial,
                                                  const float* __restrict__ b_exp,
                                                  int* __restrict__ topi,
                                                  float* __restrict__ topg,
                                                  float* __restrict__ bias_y,
                                                  float* __restrict__ loss_out) {
    __shared__ float gS[64 * 8];
    __shared__ int i0S[64], i1S[64];
    __shared__ float g0S[64], g1S[64];
    int tid = threadIdx.x;
    if (tid < 64) {
        float lg[8];
        #pragma unroll
        for (int e = 0; e < 8; e++)
            lg[e] = partial[(tid * 4 + 0) * 8 + e] + partial[(tid * 4 + 1) * 8 + e] +
                    partial[(tid * 4 + 2) * 8 + e] + partial[(tid * 4 + 3) * 8 + e];
        int i0 = 0; float v0 = lg[0];
        #pragma unroll
        for (int e = 1; e < 8; e++) if (lg[e] > v0) { v0 = lg[e]; i0 = e; }
        int i1 = -1; float v1 = -1e30f;
        #pragma unroll
        for (int e = 0; e < 8; e++) if (e != i0 && lg[e] > v1) { v1 = lg[e]; i1 = e; }
        if (i1 < 0) i1 = (i0 + 1) & 7;
        float e2 = expf(v1 - v0);
        float g0 = 1.f / (1.f + e2);
        float g1 = e2 / (1.f + e2);
        #pragma unroll
        for (int e = 0; e < 8; e++) gS[tid * 8 + e] = 0.f;
        gS[tid * 8 + i0] = g0;
        gS[tid * 8 + i1] = g1;
        i0S[tid] = i0; i1S[tid] = i1; g0S[tid] = g0; g1S[tid] = g1;
        topi[tid * 2] = i0; topi[tid * 2 + 1] = i1;
        topg[tid * 2] = g0; topg[tid * 2 + 1] = g1;
    }
    __syncthreads();
    for (int idx = tid; idx < 4096; idx += 256) {
        int b = idx >> 6, h = idx & 63;
        bias_y[idx] = g0S[b] * b_exp[i0S[b] * 64 + h] + g1S[b] * b_exp[i1S[b] * 64 + h];
    }
    if (tid < 64) {
        float g[8];
        #pragma unroll
        for (int e = 0; e < 8; e++) g[e] = gS[tid * 8 + e];
        float imp[8], ld[8];
        #pragma unroll
        for (int e = 0; e < 8; e++) {
            imp[e] = wsum(g[e]);
            ld[e]  = wsum(g[e] > 0.f ? 1.f : 0.f);
        }
        if (tid == 0) {
            float l = 0.f;
            {
                float s = 0.f;
                #pragma unroll
                for (int e = 0; e < 8; e++) s += imp[e];
                float mn = s / 8.f, v = 0.f;
                #pragma unroll
                for (int e = 0; e < 8; e++) { float d = imp[e] - mn; v += d * d; }
                l += (v / 7.f) / (mn * mn + 1e-10f);
            }
            {
                float s = 0.f;
                #pragma unroll
                for (int e = 0; e < 8; e++) s += ld[e];
                float mn = s / 8.f, v = 0.f;
                #pragma unroll
                for (int e = 0; e < 8; e++) { float d = ld[e] - mn; v += d * d; }
                l += (v / 7.f) / (mn * mn + 1e-10f);
            }
            loss_out[0] = 0.01f * l;
        }
    }
}

// ---------- 2. MFMA GEMMs: bid<512: pair=(bid>>1) rows, kind=bid&1 (0=sh f32, 1=y bf16);
//             bid>=512: kind2 rgb -> out plane. 64x64 tile, bf16 16x16x32 MFMA. ----------
__global__ __launch_bounds__(256) void k_gemm3(const float* __restrict__ dte,
                                               const float* __restrict__ x,
                                               const float* __restrict__ W_sh,
                                               const float* __restrict__ b_sh,
                                               const float* __restrict__ W_exp,
                                               const int* __restrict__ topi,
                                               const float* __restrict__ topg,
                                               const float* __restrict__ bias_y,
                                               const float* __restrict__ W_rgb,
                                               const float* __restrict__ b_rgb,
                                               float* __restrict__ buf_sh,
                                               u16* __restrict__ buf_y,
                                               float* __restrict__ out_rgb) {
    __shared__ u16 As[64 * 40];   // A rows, stride 40 u16 (80 B, 16B-aligned, 2-way banks = free)
    __shared__ u16 Wt[64 * 40];   // W^T: Wt[n][k], stride 40
    int bid = blockIdx.x;
    int kind, row0;
    if (bid < 512) { kind = bid & 1; row0 = (bid >> 1) * 64; }
    else           { kind = 2;       row0 = (bid - 512) * 64; }
    int b = row0 >> 8;
    int tid = threadIdx.x, wv = tid >> 6, lane = tid & 63;
    int m = lane & 15, quad = lane >> 4;

    const float* A = (kind == 2) ? x : dte;
    const float* W0 = (kind == 2) ? W_rgb : W_sh;
    const float* W1 = W0;
    float g0 = 0.f, g1 = 0.f;
    if (kind == 1) {
        W0 = W_exp + (size_t)topi[2 * b] * 49152;
        W1 = W_exp + (size_t)topi[2 * b + 1] * 49152;
        g0 = topg[2 * b]; g1 = topg[2 * b + 1];
    }

    f32x4 acc0 = {0.f, 0.f, 0.f, 0.f}, acc1 = acc0, acc2 = acc0, acc3 = acc0;

    for (int kc = 0; kc < 24; kc++) {
        __syncthreads();
        // stage A: 64 rows x 32 k (f32 -> bf16)
        #pragma unroll
        for (int j = 0; j < 2; j++) {
            int e4 = tid + j * 256;          // 0..511
            int r = e4 >> 3, kq = e4 & 7;    // 64 rows x 8 float4
            float4 v = *(const float4*)(A + (size_t)(row0 + r) * 768 + kc * 32 + kq * 4);
            u32* d = (u32*)&As[r * 40 + kq * 4];
            d[0] = pack2(v.x, v.y);
            d[1] = pack2(v.z, v.w);
        }
        // stage W^T: 32 k x 64 n -> Wt[n][k] bf16
        #pragma unroll
        for (int j = 0; j < 2; j++) {
            int e4 = tid + j * 256;
            int k = e4 >> 4, n4 = (e4 & 15) * 4;   // 32 k x 16 float4
            size_t off = (size_t)(kc * 32 + k) * 64 + n4;
            float4 wvv;
            if (kind == 1) {
                float4 a = *(const float4*)(W0 + off);
                float4 c = *(const float4*)(W1 + off);
                wvv.x = g0 * a.x + g1 * c.x; wvv.y = g0 * a.y + g1 * c.y;
                wvv.z = g0 * a.z + g1 * c.z; wvv.w = g0 * a.w + g1 * c.w;
            } else {
                wvv = *(const float4*)(W0 + off);
            }
            Wt[(n4 + 0) * 40 + k] = f2bf(wvv.x);
            Wt[(n4 + 1) * 40 + k] = f2bf(wvv.y);
            Wt[(n4 + 2) * 40 + k] = f2bf(wvv.z);
            Wt[(n4 + 3) * 40 + k] = f2bf(wvv.w);
        }
        __syncthreads();
        // compute: wave wv -> rows [wv*16, wv*16+16), 4 col tiles
        bf16x8 a = *(const bf16x8*)&As[(wv * 16 + m) * 40 + quad * 8];
        bf16x8 b0 = *(const bf16x8*)&Wt[(0 * 16 + m) * 40 + quad * 8];
        bf16x8 b1 = *(const bf16x8*)&Wt[(1 * 16 + m) * 40 + quad * 8];
        bf16x8 b2 = *(const bf16x8*)&Wt[(2 * 16 + m) * 40 + quad * 8];
        bf16x8 b3 = *(const bf16x8*)&Wt[(3 * 16 + m) * 40 + quad * 8];
        acc0 = __builtin_amdgcn_mfma_f32_16x16x32_bf16(a, b0, acc0, 0, 0, 0);
        acc1 = __builtin_amdgcn_mfma_f32_16x16x32_bf16(a, b1, acc1, 0, 0, 0);
        acc2 = __builtin_amdgcn_mfma_f32_16x16x32_bf16(a, b2, acc2, 0, 0, 0);
        acc3 = __builtin_amdgcn_mfma_f32_16x16x32_bf16(a, b3, acc3, 0, 0, 0);
    }

    // epilogue: C[row0 + wv*16 + quad*4 + reg][t*16 + m]
    f32x4 accs[4] = {acc0, acc1, acc2, acc3};
    #pragma unroll
    for (int t = 0; t < 4; t++) {
        int col = t * 16 + m;
        float bias;
        if (kind == 0)      bias = b_sh[col];
        else if (kind == 1) bias = bias_y[b * 64 + col];
        else                bias = b_rgb[col];
        #pragma unroll
        for (int i = 0; i < 4; i++) {
            int r = row0 + wv * 16 + quad * 4 + i;
            float val = accs[t][i] + bias;
            if (kind == 0)      buf_sh[(size_t)r * 64 + col] = val;
            else if (kind == 1) buf_y[(size_t)r * 64 + col] = f2bf(val);
            else                out_rgb[(size_t)r * 64 + col] = val;
        }
    }
}

// ---------- 3. LN + W_px -> t1, t2 (bf16); 32-row tiles, grid 512 ----------
__global__ __launch_bounds__(256) void k_lnpx(const float* __restrict__ buf_sh,
                                              const float* __restrict__ ln_g,
                                              const float* __restrict__ ln_b,
                                              const float* __restrict__ W_px,
                                              const float* __restrict__ b_px,
                                              u16* __restrict__ t1, u16* __restrict__ t2) {
    __shared__ float T[32 * 68];
    __shared__ float Wpx[8192];
    int r0 = blockIdx.x * 32;
    int tid = threadIdx.x, w = tid >> 6, lane = tid & 63;
    #pragma unroll
    for (int j = 0; j < 8; j++) {
        int e4 = tid + j * 256;
        *(float4*)(Wpx + e4 * 4) = *(const float4*)(W_px + e4 * 4);
    }
    float lnG = ln_g[lane], lnB = ln_b[lane];
    for (int i = 0; i < 8; i++) {
        int l = w * 8 + i;
        float v = buf_sh[(size_t)(r0 + l) * 64 + lane];
        float mean = wsum(v) * (1.f / 64.f);
        float d = v - mean;
        float var = wsum(d * d) * (1.f / 64.f);
        T[l * 68 + lane] = d * rsqrtf(var + 1e-6f) * lnG + lnB;
    }
    __syncthreads();
    int rg = tid >> 4, cg = tid & 15;
    float acc1[2][4] = {}, acc2[2][4] = {};
    const float* tr = T + rg * 2 * 68;
    #pragma unroll 4
    for (int kk = 0; kk < 64; kk++) {
        float a0 = tr[kk], a1 = tr[68 + kk];
        float4 w1 = *(const float4*)(Wpx + kk * 128 + cg * 4);
        float4 w2 = *(const float4*)(Wpx + kk * 128 + 64 + cg * 4);
        acc1[0][0] += a0 * w1.x; acc1[0][1] += a0 * w1.y; acc1[0][2] += a0 * w1.z; acc1[0][3] += a0 * w1.w;
        acc1[1][0] += a1 * w1.x; acc1[1][1] += a1 * w1.y; acc1[1][2] += a1 * w1.z; acc1[1][3] += a1 * w1.w;
        acc2[0][0] += a0 * w2.x; acc2[0][1] += a0 * w2.y; acc2[0][2] += a0 * w2.z; acc2[0][3] += a0 * w2.w;
        acc2[1][0] += a1 * w2.x; acc2[1][1] += a1 * w2.y; acc2[1][2] += a1 * w2.z; acc2[1][3] += a1 * w2.w;
    }
    float4 b1 = *(const float4*)(b_px + cg * 4);
    float4 b2 = *(const float4*)(b_px + 64 + cg * 4);
    #pragma unroll
    for (int i = 0; i < 2; i++) {
        int r = r0 + rg * 2 + i;
        u32* d1 = (u32*)(t1 + (size_t)r * 64 + cg * 4);
        d1[0] = pack2(acc1[i][0] + b1.x, acc1[i][1] + b1.y);
        d1[1] = pack2(acc1[i][2] + b1.z, acc1[i][3] + b1.w);
        u32* d2 = (u32*)(t2 + (size_t)r * 64 + cg * 4);
        d2[0] = pack2(acc2[i][0] + b2.x, acc2[i][1] + b2.y);
        d2[1] = pack2(acc2[i][2] + b2.z, acc2[i][3] + b2.w);
    }
}

// ---------- 4. tail (unchanged from R7) ----------
__global__ __launch_bounds__(256) void k_tail(const u16* __restrict__ t1,
                                              const u16* __restrict__ t2,
                                              const float* __restrict__ conv_sh,
                                              const float* __restrict__ W_pxx,
                                              const float* __restrict__ b_pxx,
                                              const float* __restrict__ buf_sh,
                                              const u16* __restrict__ buf_y,
                                              const float* __restrict__ W_dte,
                                              const float* __restrict__ b_dte,
                                              const float* __restrict__ W_dteall,
                                              const float* __restrict__ b_dteall,
                                              const float* __restrict__ W_fx,
                                              const float* __restrict__ b_fx,
                                              const float* __restrict__ W_fmod,
                                              const float* __restrict__ b_fmod,
                                              const float* __restrict__ W_fxx,
                                              const float* __restrict__ b_fxx,
                                              float* __restrict__ out) {
    __shared__ float B0[32 * 68];
    __shared__ float B1[32 * 68];
    __shared__ float B2[32 * 68];
    __shared__ float RS[32 * 64];
    int r0 = blockIdx.x * 32;
    int tid = threadIdx.x, w = tid >> 6, lane = tid & 63;
    int rg = tid >> 4, cg = tid & 15;

    {
        float c0 = conv_sh[lane * 9 + 0], c1 = conv_sh[lane * 9 + 1], c2 = conv_sh[lane * 9 + 2];
        float c3 = conv_sh[lane * 9 + 3], c4 = conv_sh[lane * 9 + 4], c5 = conv_sh[lane * 9 + 5];
        float c6 = conv_sh[lane * 9 + 6], c7 = conv_sh[lane * 9 + 7], c8 = conv_sh[lane * 9 + 8];
        for (int i = 0; i < 8; i++) {
            int l = w * 8 + i;
            int gr = r0 + l;
            int pix = gr & 255, ii = pix >> 4, jj = pix & 15;
            const u16* p = t1 + (size_t)gr * 64 + lane;
            float c = c4 * bf2f(p[0]);
            if (ii > 0) {
                c += c1 * bf2f(p[-1024]);
                if (jj > 0)  c += c0 * bf2f(p[-1024 - 64]);
                if (jj < 15) c += c2 * bf2f(p[-1024 + 64]);
            }
            if (jj > 0)  c += c3 * bf2f(p[-64]);
            if (jj < 15) c += c5 * bf2f(p[64]);
            if (ii < 15) {
                c += c7 * bf2f(p[1024]);
                if (jj > 0)  c += c6 * bf2f(p[1024 - 64]);
                if (jj < 15) c += c8 * bf2f(p[1024 + 64]);
            }
            B0[l * 68 + lane] = gelu_f(c) * bf2f(t2[(size_t)gr * 64 + lane]);
        }
    }
    __syncthreads();

    {
        float acc[2][4] = {};
        const float* ur = B0 + rg * 2 * 68;
        #pragma unroll 8
        for (int kk = 0; kk < 64; kk++) {
            float a0 = ur[kk], a1 = ur[68 + kk];
            float4 wvv = *(const float4*)(W_pxx + kk * 64 + cg * 4);
            acc[0][0] += a0 * wvv.x; acc[0][1] += a0 * wvv.y; acc[0][2] += a0 * wvv.z; acc[0][3] += a0 * wvv.w;
            acc[1][0] += a1 * wvv.x; acc[1][1] += a1 * wvv.y; acc[1][2] += a1 * wvv.z; acc[1][3] += a1 * wvv.w;
        }
        float4 bp = *(const float4*)(b_pxx + cg * 4);
        #pragma unroll
        for (int i = 0; i < 2; i++) {
            int lr = rg * 2 + i;
            float4 shv = *(const float4*)(buf_sh + (size_t)(r0 + lr) * 64 + cg * 4);
            *(float4*)(B1 + lr * 68 + cg * 4) =
                make_float4(acc[i][0] + bp.x + shv.x, acc[i][1] + bp.y + shv.y,
                            acc[i][2] + bp.z + shv.z, acc[i][3] + bp.w + shv.w);
        }
    }
    __syncthreads();

    #pragma unroll
    for (int j = 0; j < 8; j++) {
        int e = tid + j * 256;
        int l = e >> 6, c = e & 63;
        B0[l * 68 + c] = bf2f(buf_y[(size_t)(r0 + l) * 64 + c]);
    }
    __syncthreads();

    {
        float acc[2][4] = {};
        const float* yr = B0 + rg * 2 * 68;
        const float* sr = B1 + rg * 2 * 68;
        #pragma unroll 4
        for (int kk = 0; kk < 64; kk++) {
            float y0 = yr[kk], y1 = yr[68 + kk];
            float s0 = sr[kk], s1 = sr[68 + kk];
            float4 w1 = *(const float4*)(W_dte + kk * 64 + cg * 4);
            float4 w2 = *(const float4*)(W_dteall + kk * 64 + cg * 4);
            acc[0][0] += y0 * w1.x + s0 * w2.x; acc[0][1] += y0 * w1.y + s0 * w2.y;
            acc[0][2] += y0 * w1.z + s0 * w2.z; acc[0][3] += y0 * w1.w + s0 * w2.w;
            acc[1][0] += y1 * w1.x + s1 * w2.x; acc[1][1] += y1 * w1.y + s1 * w2.y;
            acc[1][2] += y1 * w1.z + s1 * w2.z; acc[1][3] += y1 * w1.w + s1 * w2.w;
        }
        float4 bd1 = *(const float4*)(b_dte + cg * 4);
        float4 bd2 = *(const float4*)(b_dteall + cg * 4);
        #pragma unroll
        for (int i = 0; i < 2; i++) {
            int lr = rg * 2 + i;
            *(float4*)(B2 + lr * 68 + cg * 4) =
                make_float4(gelu_f(acc[i][0] + bd1.x + bd2.x), gelu_f(acc[i][1] + bd1.y + bd2.y),
                            gelu_f(acc[i][2] + bd1.z + bd2.z), gelu_f(acc[i][3] + bd1.w + bd2.w));
        }
    }
    __syncthreads();

    #pragma unroll
    for (int j = 0; j < 2; j++) {
        int e4 = tid + j * 256;
        int l = e4 >> 4, c4i = e4 & 15;
        float4 rv = *(const float4*)(out + (size_t)(r0 + l) * 64 + c4i * 4);
        *(float4*)(RS + l * 64 + c4i * 4) = rv;
        B1[l * 68 + c4i * 4 + 0] = gelu_f(rv.x);
        B1[l * 68 + c4i * 4 + 1] = gelu_f(rv.y);
        B1[l * 68 + c4i * 4 + 2] = gelu_f(rv.z);
        B1[l * 68 + c4i * 4 + 3] = gelu_f(rv.w);
    }
    __syncthreads();

    {
        float accA[2][4] = {}, accM[2][4] = {};
        const float* ga = B1 + rg * 2 * 68;
        const float* gm = B2 + rg * 2 * 68;
        #pragma unroll 4
        for (int kk = 0; kk < 64; kk++) {
            float a0 = ga[kk], a1 = ga[68 + kk];
            float m0 = gm[kk], m1 = gm[68 + kk];
            float4 wa = *(const float4*)(W_fx + kk * 64 + cg * 4);
            float4 wm = *(const float4*)(W_fmod + kk * 64 + cg * 4);
            accA[0][0] += a0 * wa.x; accA[0][1] += a0 * wa.y; accA[0][2] += a0 * wa.z; accA[0][3] += a0 * wa.w;
            accA[1][0] += a1 * wa.x; accA[1][1] += a1 * wa.y; accA[1][2] += a1 * wa.z; accA[1][3] += a1 * wa.w;
            accM[0][0] += m0 * wm.x; accM[0][1] += m0 * wm.y; accM[0][2] += m0 * wm.z; accM[0][3] += m0 * wm.w;
            accM[1][0] += m1 * wm.x; accM[1][1] += m1 * wm.y; accM[1][2] += m1 * wm.z; accM[1][3] += m1 * wm.w;
        }
        float4 bx = *(const float4*)(b_fx + cg * 4);
        float4 bm = *(const float4*)(b_fmod + cg * 4);
        #pragma unroll
        for (int i = 0; i < 2; i++) {
            int lr = rg * 2 + i;
            float a0 = accA[i][0] + bx.x, a1 = accA[i][1] + bx.y, a2 = accA[i][2] + bx.z, a3 = accA[i][3] + bx.w;
            float m0 = accM[i][0] + bm.x, m1 = accM[i][1] + bm.y, m2 = accM[i][2] + bm.z, m3 = accM[i][3] + bm.w;
            *(float4*)(B0 + lr * 68 + cg * 4) =
                make_float4(gelu_f(m0) * a0, gelu_f(m1) * a1, gelu_f(m2) * a2, gelu_f(m3) * a3);
        }
    }
    __syncthreads();

    {
        float acc[2][4] = {};
        const float* pr = B0 + rg * 2 * 68;
        #pragma unroll 8
        for (int kk = 0; kk < 64; kk++) {
            float p0 = pr[kk], p1 = pr[68 + kk];
            float4 wvv = *(const float4*)(W_fxx + kk * 64 + cg * 4);
            acc[0][0] += p0 * wvv.x; acc[0][1] += p0 * wvv.y; acc[0][2] += p0 * wvv.z; acc[0][3] += p0 * wvv.w;
            acc[1][0] += p1 * wvv.x; acc[1][1] += p1 * wvv.y; acc[1][2] += p1 * wvv.z; acc[1][3] += p1 * wvv.w;
        }
        float4 bo = *(const float4*)(b_fxx + cg * 4);
        #pragma unroll
        for (int i = 0; i < 2; i++) {
            int lr = rg * 2 + i;
            *(float4*)(out + (size_t)(r0 + lr) * 64 + cg * 4) =
                make_float4(acc[i][0] + bo.x + RS[lr * 64 + cg * 4 + 0],
                            acc[i][1] + bo.y + RS[lr * 64 + cg * 4 + 1],
                            acc[i][2] + bo.z + RS[lr * 64 + cg * 4 + 2],
                            acc[i][3] + bo.w + RS[lr * 64 + cg * 4 + 3]);
        }
    }
}

extern "C" void kernel_launch(void* const* d_in, const int* in_sizes, int n_in,
                              void* d_out, int out_size, void* d_ws, size_t ws_size,
                              hipStream_t stream) {
    const float* x       = (const float*)d_in[0];
    const float* dte     = (const float*)d_in[1];
    const float* w_gate  = (const float*)d_in[2];
    const float* W_exp   = (const float*)d_in[3];
    const float* b_exp   = (const float*)d_in[4];
    const float* W_sh    = (const float*)d_in[5];
    const float* b_sh    = (const float*)d_in[6];
    const float* ln_g    = (const float*)d_in[7];
    const float* ln_b    = (const float*)d_in[8];
    const float* W_px    = (const float*)d_in[9];
    const float* b_px    = (const float*)d_in[10];
    const float* conv_sh = (const float*)d_in[11];
    const float* W_pxx   = (const float*)d_in[12];
    const float* b_pxx   = (const float*)d_in[13];
    const float* W_dte   = (const float*)d_in[14];
    const float* b_dte   = (const float*)d_in[15];
    const float* W_dteall= (const float*)d_in[16];
    const float* b_dteall= (const float*)d_in[17];
    const float* W_rgb   = (const float*)d_in[18];
    const float* b_rgb   = (const float*)d_in[19];
    const float* W_fx    = (const float*)d_in[20];
    const float* b_fx    = (const float*)d_in[21];
    const float* W_fmod  = (const float*)d_in[22];
    const float* b_fmod  = (const float*)d_in[23];
    const float* W_fxx   = (const float*)d_in[24];
    const float* b_fxx   = (const float*)d_in[25];

    float* out = (float*)d_out;     // [0,1048576) plane + loss at [1048576]

    float* wsf    = (float*)d_ws;
    float* partial= wsf;                         // 2048
    int*   topi   = (int*)(wsf + 2048);          // 128
    float* topg   = wsf + 2176;                  // 128
    float* bias_y = wsf + 2304;                  // 4096
    float* buf_sh = wsf + 8192;                  // 1048576 f32
    u16*   buf_y  = (u16*)(wsf + 8192 + 1048576);
    u16*   t1     = (u16*)(wsf + 8192 + 1048576 + 524288);
    u16*   t2     = (u16*)(wsf + 8192 + 1048576 + 524288*2);

    hipLaunchKernelGGL(k_gate_part, dim3(256), dim3(256), 0, stream, dte, w_gate, partial);
    hipLaunchKernelGGL(k_gate_fin, dim3(1), dim3(256), 0, stream,
                       partial, b_exp, topi, topg, bias_y, out + 1048576);
    hipLaunchKernelGGL(k_gemm3, dim3(768), dim3(256), 0, stream,
                       dte, x, W_sh, b_sh, W_exp, topi, topg, bias_y, W_rgb, b_rgb,
                       buf_sh, buf_y, out);
    hipLaunchKernelGGL(k_lnpx, dim3(512), dim3(256), 0, stream,
                       buf_sh, ln_g, ln_b, W_px, b_px, t1, t2);
    hipLaunchKernelGGL(k_tail, dim3(512), dim3(256), 0, stream,
                       t1, t2, conv_sh, W_pxx, b_pxx, buf_sh, buf_y,
                       W_dte, b_dte, W_dteall, b_dteall,
                       W_fx, b_fx, W_fmod, b_fmod, W_fxx, b_fxx, out);

    (void)in_sizes; (void)n_in; (void)out_size; (void)ws_size;
}

// Round 9
// 255.667 us; speedup vs baseline: 5.5459x; 1.0902x over previous
//
#include <hip/hip_runtime.h>
#include <math.h>

typedef unsigned short u16;
typedef unsigned int u32;
typedef __attribute__((ext_vector_type(8))) short bf16x8;
typedef __attribute__((ext_vector_type(4))) float f32x4;

// B=64, L=256, DIN=768, H=64, E=8, K=2, S=16; BL=16384. All inputs f32, output f32.

__device__ __forceinline__ float bf2f(u16 u) {
    union { u32 i; float f; } x; x.i = ((u32)u) << 16; return x.f;
}
__device__ __forceinline__ u16 f2bf(float f) {
    union { float f; u32 i; } x; x.f = f;
    u32 i = x.i;
    return (u16)((i + 0x7fffu + ((i >> 16) & 1u)) >> 16);
}
__device__ __forceinline__ u32 pack2(float a, float b) {
    return (u32)f2bf(a) | ((u32)f2bf(b) << 16);
}
__device__ __forceinline__ float wsum(float v) {
    #pragma unroll
    for (int o = 1; o < 64; o <<= 1) v += __shfl_xor(v, o, 64);
    return v;
}
__device__ __forceinline__ float gelu_f(float x) {
    return 0.5f * x * (1.0f + erff(x * 0.70710678118654752440f));
}

// ---------- 1a. partial gating ----------
__global__ __launch_bounds__(256) void k_gate_part(const float* __restrict__ dte,
                                                   const float* __restrict__ w_gate,
                                                   float* __restrict__ partial) {
    __shared__ float dmeanS[64];
    int p = blockIdx.x, tid = threadIdx.x, w = tid >> 6, lane = tid & 63;
    for (int i = 0; i < 16; i++) {
        int l = w * 16 + i;
        const float* pr = dte + ((size_t)p * 64 + l) * 768;
        float s = 0.f;
        #pragma unroll
        for (int j = 0; j < 3; j++) {
            float4 v = *(const float4*)(pr + (lane + j * 64) * 4);
            s += v.x + v.y + v.z + v.w;
        }
        s = wsum(s);
        if (lane == 0) dmeanS[l] = s * (1.f / 768.f);
    }
    __syncthreads();
    if (w == 0) {
        float dm = dmeanS[lane];
        int wl = (p & 3) * 64 + lane;
        #pragma unroll
        for (int e = 0; e < 8; e++) {
            float s = wsum(dm * w_gate[wl * 8 + e]);
            if (lane == 0) partial[p * 8 + e] = s;
        }
    }
}

// ---------- 1b. finalize gates + loss ----------
__global__ __launch_bounds__(256) void k_gate_fin(const float* __restrict__ partial,
                                                  const float* __restrict__ b_exp,
                                                  int* __restrict__ topi,
                                                  float* __restrict__ topg,
                                                  float* __restrict__ bias_y,
                                                  float* __restrict__ loss_out) {
    __shared__ float gS[64 * 8];
    __shared__ int i0S[64], i1S[64];
    __shared__ float g0S[64], g1S[64];
    int tid = threadIdx.x;
    if (tid < 64) {
        float lg[8];
        #pragma unroll
        for (int e = 0; e < 8; e++)
            lg[e] = partial[(tid * 4 + 0) * 8 + e] + partial[(tid * 4 + 1) * 8 + e] +
                    partial[(tid * 4 + 2) * 8 + e] + partial[(tid * 4 + 3) * 8 + e];
        int i0 = 0; float v0 = lg[0];
        #pragma unroll
        for (int e = 1; e < 8; e++) if (lg[e] > v0) { v0 = lg[e]; i0 = e; }
        int i1 = -1; float v1 = -1e30f;
        #pragma unroll
        for (int e = 0; e < 8; e++) if (e != i0 && lg[e] > v1) { v1 = lg[e]; i1 = e; }
        if (i1 < 0) i1 = (i0 + 1) & 7;
        float e2 = expf(v1 - v0);
        float g0 = 1.f / (1.f + e2);
        float g1 = e2 / (1.f + e2);
        #pragma unroll
        for (int e = 0; e < 8; e++) gS[tid * 8 + e] = 0.f;
        gS[tid * 8 + i0] = g0;
        gS[tid * 8 + i1] = g1;
        i0S[tid] = i0; i1S[tid] = i1; g0S[tid] = g0; g1S[tid] = g1;
        topi[tid * 2] = i0; topi[tid * 2 + 1] = i1;
        topg[tid * 2] = g0; topg[tid * 2 + 1] = g1;
    }
    __syncthreads();
    for (int idx = tid; idx < 4096; idx += 256) {
        int b = idx >> 6, h = idx & 63;
        bias_y[idx] = g0S[b] * b_exp[i0S[b] * 64 + h] + g1S[b] * b_exp[i1S[b] * 64 + h];
    }
    if (tid < 64) {
        float g[8];
        #pragma unroll
        for (int e = 0; e < 8; e++) g[e] = gS[tid * 8 + e];
        float imp[8], ld[8];
        #pragma unroll
        for (int e = 0; e < 8; e++) {
            imp[e] = wsum(g[e]);
            ld[e]  = wsum(g[e] > 0.f ? 1.f : 0.f);
        }
        if (tid == 0) {
            float l = 0.f;
            {
                float s = 0.f;
                #pragma unroll
                for (int e = 0; e < 8; e++) s += imp[e];
                float mn = s / 8.f, v = 0.f;
                #pragma unroll
                for (int e = 0; e < 8; e++) { float d = imp[e] - mn; v += d * d; }
                l += (v / 7.f) / (mn * mn + 1e-10f);
            }
            {
                float s = 0.f;
                #pragma unroll
                for (int e = 0; e < 8; e++) s += ld[e];
                float mn = s / 8.f, v = 0.f;
                #pragma unroll
                for (int e = 0; e < 8; e++) { float d = ld[e] - mn; v += d * d; }
                l += (v / 7.f) / (mn * mn + 1e-10f);
            }
            loss_out[0] = 0.01f * l;
        }
    }
}

// ---------- 2. MFMA GEMMs, BK=64, conflict-free staging, register prefetch.
//   bid<512: pair=(bid>>1) rows, kind=bid&1 (0=sh f32, 1=y bf16);
//   bid>=512: kind2 rgb -> out plane. ----------
__global__ __launch_bounds__(256) void k_gemm3(const float* __restrict__ dte,
                                               const float* __restrict__ x,
                                               const float* __restrict__ W_sh,
                                               const float* __restrict__ b_sh,
                                               const float* __restrict__ W_exp,
                                               const int* __restrict__ topi,
                                               const float* __restrict__ topg,
                                               const float* __restrict__ bias_y,
                                               const float* __restrict__ W_rgb,
                                               const float* __restrict__ b_rgb,
                                               float* __restrict__ buf_sh,
                                               u16* __restrict__ buf_y,
                                               float* __restrict__ out_rgb) {
    __shared__ u16 As[64 * 72];   // A[r][k], stride 72 u16 (144 B, 16B-aligned)
    __shared__ u16 Wt[64 * 72];   // W^T[n][k], stride 72
    int bid = blockIdx.x;
    int kind, row0;
    if (bid < 512) { kind = bid & 1; row0 = (bid >> 1) * 64; }
    else           { kind = 2;       row0 = (bid - 512) * 64; }
    int b = row0 >> 8;
    int tid = threadIdx.x, wv = tid >> 6, lane = tid & 63;
    int m = lane & 15, quad = lane >> 4;

    const float* A = (kind == 2) ? x : dte;
    const float* W0 = (kind == 2) ? W_rgb : W_sh;
    const float* W1 = W0;
    float g0 = 0.f, g1 = 0.f;
    if (kind == 1) {
        W0 = W_exp + (size_t)topi[2 * b] * 49152;
        W1 = W_exp + (size_t)topi[2 * b + 1] * 49152;
        g0 = topg[2 * b]; g1 = topg[2 * b + 1];
    }

    // prefetch registers
    float4 pa[2][2];        // A: 2 chunks x 8 floats
    float  pw[16];          // W: 16 consecutive k for one n
    const int a_r  = tid >> 3;            // A chunk 0 row (chunk 1: +32)
    const int a_k8 = (tid & 7) * 8;       // k offset
    const int w_n  = tid & 63;
    const int w_k0 = (tid >> 6) * 16;

    auto loadA = [&](int kc) {
        #pragma unroll
        for (int j = 0; j < 2; j++) {
            const float* src = A + (size_t)(row0 + a_r + j * 32) * 768 + kc * 64 + a_k8;
            pa[j][0] = *(const float4*)(src);
            pa[j][1] = *(const float4*)(src + 4);
        }
    };
    auto loadW = [&](int kc) {
        if (kind == 1) {
            #pragma unroll
            for (int j = 0; j < 16; j++) {
                size_t off = (size_t)(kc * 64 + w_k0 + j) * 64 + w_n;
                pw[j] = g0 * W0[off] + g1 * W1[off];
            }
        } else {
            #pragma unroll
            for (int j = 0; j < 16; j++)
                pw[j] = W0[(size_t)(kc * 64 + w_k0 + j) * 64 + w_n];
        }
    };
    auto stageLDS = [&]() {
        #pragma unroll
        for (int j = 0; j < 2; j++) {
            uint4 d;
            d.x = pack2(pa[j][0].x, pa[j][0].y);
            d.y = pack2(pa[j][0].z, pa[j][0].w);
            d.z = pack2(pa[j][1].x, pa[j][1].y);
            d.w = pack2(pa[j][1].z, pa[j][1].w);
            *(uint4*)&As[(a_r + j * 32) * 72 + a_k8] = d;
        }
        uint4 d0, d1;
        d0.x = pack2(pw[0],  pw[1]);  d0.y = pack2(pw[2],  pw[3]);
        d0.z = pack2(pw[4],  pw[5]);  d0.w = pack2(pw[6],  pw[7]);
        d1.x = pack2(pw[8],  pw[9]);  d1.y = pack2(pw[10], pw[11]);
        d1.z = pack2(pw[12], pw[13]); d1.w = pack2(pw[14], pw[15]);
        *(uint4*)&Wt[w_n * 72 + w_k0]     = d0;
        *(uint4*)&Wt[w_n * 72 + w_k0 + 8] = d1;
    };

    f32x4 acc0 = {0.f, 0.f, 0.f, 0.f}, acc1 = acc0, acc2 = acc0, acc3 = acc0;

    loadA(0); loadW(0);
    for (int kc = 0; kc < 12; kc++) {
        __syncthreads();            // previous compute done reading LDS
        stageLDS();
        __syncthreads();            // staged data visible
        if (kc < 11) { loadA(kc + 1); loadW(kc + 1); }   // prefetch overlaps MFMAs
        const int ar = (wv * 16 + m) * 72;
        bf16x8 a0 = *(const bf16x8*)&As[ar + quad * 8];
        bf16x8 a1 = *(const bf16x8*)&As[ar + 32 + quad * 8];
        #pragma unroll
        for (int t = 0; t < 4; t++) {
            const int br = (t * 16 + m) * 72;
            bf16x8 b0 = *(const bf16x8*)&Wt[br + quad * 8];
            bf16x8 b1 = *(const bf16x8*)&Wt[br + 32 + quad * 8];
            f32x4* accp = (t == 0) ? &acc0 : (t == 1) ? &acc1 : (t == 2) ? &acc2 : &acc3;
            *accp = __builtin_amdgcn_mfma_f32_16x16x32_bf16(a0, b0, *accp, 0, 0, 0);
            *accp = __builtin_amdgcn_mfma_f32_16x16x32_bf16(a1, b1, *accp, 0, 0, 0);
        }
    }

    // epilogue: C[row0 + wv*16 + quad*4 + i][t*16 + m]
    f32x4 accs[4] = {acc0, acc1, acc2, acc3};
    #pragma unroll
    for (int t = 0; t < 4; t++) {
        int col = t * 16 + m;
        float bias;
        if (kind == 0)      bias = b_sh[col];
        else if (kind == 1) bias = bias_y[b * 64 + col];
        else                bias = b_rgb[col];
        #pragma unroll
        for (int i = 0; i < 4; i++) {
            int r = row0 + wv * 16 + quad * 4 + i;
            float val = accs[t][i] + bias;
            if (kind == 0)      buf_sh[(size_t)r * 64 + col] = val;
            else if (kind == 1) buf_y[(size_t)r * 64 + col] = f2bf(val);
            else                out_rgb[(size_t)r * 64 + col] = val;
        }
    }
}

// ---------- 3. LN + W_px -> t1, t2 (bf16); 32-row tiles, grid 512 ----------
__global__ __launch_bounds__(256) void k_lnpx(const float* __restrict__ buf_sh,
                                              const float* __restrict__ ln_g,
                                              const float* __restrict__ ln_b,
                                              const float* __restrict__ W_px,
                                              const float* __restrict__ b_px,
                                              u16* __restrict__ t1, u16* __restrict__ t2) {
    __shared__ float T[32 * 68];
    __shared__ float Wpx[8192];
    int r0 = blockIdx.x * 32;
    int tid = threadIdx.x, w = tid >> 6, lane = tid & 63;
    #pragma unroll
    for (int j = 0; j < 8; j++) {
        int e4 = tid + j * 256;
        *(float4*)(Wpx + e4 * 4) = *(const float4*)(W_px + e4 * 4);
    }
    float lnG = ln_g[lane], lnB = ln_b[lane];
    for (int i = 0; i < 8; i++) {
        int l = w * 8 + i;
        float v = buf_sh[(size_t)(r0 + l) * 64 + lane];
        float mean = wsum(v) * (1.f / 64.f);
        float d = v - mean;
        float var = wsum(d * d) * (1.f / 64.f);
        T[l * 68 + lane] = d * rsqrtf(var + 1e-6f) * lnG + lnB;
    }
    __syncthreads();
    int rg = tid >> 4, cg = tid & 15;
    float acc1[2][4] = {}, acc2[2][4] = {};
    const float* tr = T + rg * 2 * 68;
    #pragma unroll 4
    for (int kk = 0; kk < 64; kk++) {
        float a0 = tr[kk], a1 = tr[68 + kk];
        float4 w1 = *(const float4*)(Wpx + kk * 128 + cg * 4);
        float4 w2 = *(const float4*)(Wpx + kk * 128 + 64 + cg * 4);
        acc1[0][0] += a0 * w1.x; acc1[0][1] += a0 * w1.y; acc1[0][2] += a0 * w1.z; acc1[0][3] += a0 * w1.w;
        acc1[1][0] += a1 * w1.x; acc1[1][1] += a1 * w1.y; acc1[1][2] += a1 * w1.z; acc1[1][3] += a1 * w1.w;
        acc2[0][0] += a0 * w2.x; acc2[0][1] += a0 * w2.y; acc2[0][2] += a0 * w2.z; acc2[0][3] += a0 * w2.w;
        acc2[1][0] += a1 * w2.x; acc2[1][1] += a1 * w2.y; acc2[1][2] += a1 * w2.z; acc2[1][3] += a1 * w2.w;
    }
    float4 b1 = *(const float4*)(b_px + cg * 4);
    float4 b2 = *(const float4*)(b_px + 64 + cg * 4);
    #pragma unroll
    for (int i = 0; i < 2; i++) {
        int r = r0 + rg * 2 + i;
        u32* d1 = (u32*)(t1 + (size_t)r * 64 + cg * 4);
        d1[0] = pack2(acc1[i][0] + b1.x, acc1[i][1] + b1.y);
        d1[1] = pack2(acc1[i][2] + b1.z, acc1[i][3] + b1.w);
        u32* d2 = (u32*)(t2 + (size_t)r * 64 + cg * 4);
        d2[0] = pack2(acc2[i][0] + b2.x, acc2[i][1] + b2.y);
        d2[1] = pack2(acc2[i][2] + b2.z, acc2[i][3] + b2.w);
    }
}

// ---------- 4. tail (unchanged) ----------
__global__ __launch_bounds__(256) void k_tail(const u16* __restrict__ t1,
                                              const u16* __restrict__ t2,
                                              const float* __restrict__ conv_sh,
                                              const float* __restrict__ W_pxx,
                                              const float* __restrict__ b_pxx,
                                              const float* __restrict__ buf_sh,
                                              const u16* __restrict__ buf_y,
                                              const float* __restrict__ W_dte,
                                              const float* __restrict__ b_dte,
                                              const float* __restrict__ W_dteall,
                                              const float* __restrict__ b_dteall,
                                              const float* __restrict__ W_fx,
                                              const float* __restrict__ b_fx,
                                              const float* __restrict__ W_fmod,
                                              const float* __restrict__ b_fmod,
                                              const float* __restrict__ W_fxx,
                                              const float* __restrict__ b_fxx,
                                              float* __restrict__ out) {
    __shared__ float B0[32 * 68];
    __shared__ float B1[32 * 68];
    __shared__ float B2[32 * 68];
    __shared__ float RS[32 * 64];
    int r0 = blockIdx.x * 32;
    int tid = threadIdx.x, w = tid >> 6, lane = tid & 63;
    int rg = tid >> 4, cg = tid & 15;

    {
        float c0 = conv_sh[lane * 9 + 0], c1 = conv_sh[lane * 9 + 1], c2 = conv_sh[lane * 9 + 2];
        float c3 = conv_sh[lane * 9 + 3], c4 = conv_sh[lane * 9 + 4], c5 = conv_sh[lane * 9 + 5];
        float c6 = conv_sh[lane * 9 + 6], c7 = conv_sh[lane * 9 + 7], c8 = conv_sh[lane * 9 + 8];
        for (int i = 0; i < 8; i++) {
            int l = w * 8 + i;
            int gr = r0 + l;
            int pix = gr & 255, ii = pix >> 4, jj = pix & 15;
            const u16* p = t1 + (size_t)gr * 64 + lane;
            float c = c4 * bf2f(p[0]);
            if (ii > 0) {
                c += c1 * bf2f(p[-1024]);
                if (jj > 0)  c += c0 * bf2f(p[-1024 - 64]);
                if (jj < 15) c += c2 * bf2f(p[-1024 + 64]);
            }
            if (jj > 0)  c += c3 * bf2f(p[-64]);
            if (jj < 15) c += c5 * bf2f(p[64]);
            if (ii < 15) {
                c += c7 * bf2f(p[1024]);
                if (jj > 0)  c += c6 * bf2f(p[1024 - 64]);
                if (jj < 15) c += c8 * bf2f(p[1024 + 64]);
            }
            B0[l * 68 + lane] = gelu_f(c) * bf2f(t2[(size_t)gr * 64 + lane]);
        }
    }
    __syncthreads();

    {
        float acc[2][4] = {};
        const float* ur = B0 + rg * 2 * 68;
        #pragma unroll 8
        for (int kk = 0; kk < 64; kk++) {
            float a0 = ur[kk], a1 = ur[68 + kk];
            float4 wvv = *(const float4*)(W_pxx + kk * 64 + cg * 4);
            acc[0][0] += a0 * wvv.x; acc[0][1] += a0 * wvv.y; acc[0][2] += a0 * wvv.z; acc[0][3] += a0 * wvv.w;
            acc[1][0] += a1 * wvv.x; acc[1][1] += a1 * wvv.y; acc[1][2] += a1 * wvv.z; acc[1][3] += a1 * wvv.w;
        }
        float4 bp = *(const float4*)(b_pxx + cg * 4);
        #pragma unroll
        for (int i = 0; i < 2; i++) {
            int lr = rg * 2 + i;
            float4 shv = *(const float4*)(buf_sh + (size_t)(r0 + lr) * 64 + cg * 4);
            *(float4*)(B1 + lr * 68 + cg * 4) =
                make_float4(acc[i][0] + bp.x + shv.x, acc[i][1] + bp.y + shv.y,
                            acc[i][2] + bp.z + shv.z, acc[i][3] + bp.w + shv.w);
        }
    }
    __syncthreads();

    #pragma unroll
    for (int j = 0; j < 8; j++) {
        int e = tid + j * 256;
        int l = e >> 6, c = e & 63;
        B0[l * 68 + c] = bf2f(buf_y[(size_t)(r0 + l) * 64 + c]);
    }
    __syncthreads();

    {
        float acc[2][4] = {};
        const float* yr = B0 + rg * 2 * 68;
        const float* sr = B1 + rg * 2 * 68;
        #pragma unroll 4
        for (int kk = 0; kk < 64; kk++) {
            float y0 = yr[kk], y1 = yr[68 + kk];
            float s0 = sr[kk], s1 = sr[68 + kk];
            float4 w1 = *(const float4*)(W_dte + kk * 64 + cg * 4);
            float4 w2 = *(const float4*)(W_dteall + kk * 64 + cg * 4);
            acc[0][0] += y0 * w1.x + s0 * w2.x; acc[0][1] += y0 * w1.y + s0 * w2.y;
            acc[0][2] += y0 * w1.z + s0 * w2.z; acc[0][3] += y0 * w1.w + s0 * w2.w;
            acc[1][0] += y1 * w1.x + s1 * w2.x; acc[1][1] += y1 * w1.y + s1 * w2.y;
            acc[1][2] += y1 * w1.z + s1 * w2.z; acc[1][3] += y1 * w1.w + s1 * w2.w;
        }
        float4 bd1 = *(const float4*)(b_dte + cg * 4);
        float4 bd2 = *(const float4*)(b_dteall + cg * 4);
        #pragma unroll
        for (int i = 0; i < 2; i++) {
            int lr = rg * 2 + i;
            *(float4*)(B2 + lr * 68 + cg * 4) =
                make_float4(gelu_f(acc[i][0] + bd1.x + bd2.x), gelu_f(acc[i][1] + bd1.y + bd2.y),
                            gelu_f(acc[i][2] + bd1.z + bd2.z), gelu_f(acc[i][3] + bd1.w + bd2.w));
        }
    }
    __syncthreads();

    #pragma unroll
    for (int j = 0; j < 2; j++) {
        int e4 = tid + j * 256;
        int l = e4 >> 4, c4i = e4 & 15;
        float4 rv = *(const float4*)(out + (size_t)(r0 + l) * 64 + c4i * 4);
        *(float4*)(RS + l * 64 + c4i * 4) = rv;
        B1[l * 68 + c4i * 4 + 0] = gelu_f(rv.x);
        B1[l * 68 + c4i * 4 + 1] = gelu_f(rv.y);
        B1[l * 68 + c4i * 4 + 2] = gelu_f(rv.z);
        B1[l * 68 + c4i * 4 + 3] = gelu_f(rv.w);
    }
    __syncthreads();

    {
        float accA[2][4] = {}, accM[2][4] = {};
        const float* ga = B1 + rg * 2 * 68;
        const float* gm = B2 + rg * 2 * 68;
        #pragma unroll 4
        for (int kk = 0; kk < 64; kk++) {
            float a0 = ga[kk], a1 = ga[68 + kk];
            float m0 = gm[kk], m1 = gm[68 + kk];
            float4 wa = *(const float4*)(W_fx + kk * 64 + cg * 4);
            float4 wm = *(const float4*)(W_fmod + kk * 64 + cg * 4);
            accA[0][0] += a0 * wa.x; accA[0][1] += a0 * wa.y; accA[0][2] += a0 * wa.z; accA[0][3] += a0 * wa.w;
            accA[1][0] += a1 * wa.x; accA[1][1] += a1 * wa.y; accA[1][2] += a1 * wa.z; accA[1][3] += a1 * wa.w;
            accM[0][0] += m0 * wm.x; accM[0][1] += m0 * wm.y; accM[0][2] += m0 * wm.z; accM[0][3] += m0 * wm.w;
            accM[1][0] += m1 * wm.x; accM[1][1] += m1 * wm.y; accM[1][2] += m1 * wm.z; accM[1][3] += m1 * wm.w;
        }
        float4 bx = *(const float4*)(b_fx + cg * 4);
        float4 bm = *(const float4*)(b_fmod + cg * 4);
        #pragma unroll
        for (int i = 0; i < 2; i++) {
            int lr = rg * 2 + i;
            float a0 = accA[i][0] + bx.x, a1 = accA[i][1] + bx.y, a2 = accA[i][2] + bx.z, a3 = accA[i][3] + bx.w;
            float m0 = accM[i][0] + bm.x, m1 = accM[i][1] + bm.y, m2 = accM[i][2] + bm.z, m3 = accM[i][3] + bm.w;
            *(float4*)(B0 + lr * 68 + cg * 4) =
                make_float4(gelu_f(m0) * a0, gelu_f(m1) * a1, gelu_f(m2) * a2, gelu_f(m3) * a3);
        }
    }
    __syncthreads();

    {
        float acc[2][4] = {};
        const float* pr = B0 + rg * 2 * 68;
        #pragma unroll 8
        for (int kk = 0; kk < 64; kk++) {
            float p0 = pr[kk], p1 = pr[68 + kk];
            float4 wvv = *(const float4*)(W_fxx + kk * 64 + cg * 4);
            acc[0][0] += p0 * wvv.x; acc[0][1] += p0 * wvv.y; acc[0][2] += p0 * wvv.z; acc[0][3] += p0 * wvv.w;
            acc[1][0] += p1 * wvv.x; acc[1][1] += p1 * wvv.y; acc[1][2] += p1 * wvv.z; acc[1][3] += p1 * wvv.w;
        }
        float4 bo = *(const float4*)(b_fxx + cg * 4);
        #pragma unroll
        for (int i = 0; i < 2; i++) {
            int lr = rg * 2 + i;
            *(float4*)(out + (size_t)(r0 + lr) * 64 + cg * 4) =
                make_float4(acc[i][0] + bo.x + RS[lr * 64 + cg * 4 + 0],
                            acc[i][1] + bo.y + RS[lr * 64 + cg * 4 + 1],
                            acc[i][2] + bo.z + RS[lr * 64 + cg * 4 + 2],
                            acc[i][3] + bo.w + RS[lr * 64 + cg * 4 + 3]);
        }
    }
}

extern "C" void kernel_launch(void* const* d_in, const int* in_sizes, int n_in,
                              void* d_out, int out_size, void* d_ws, size_t ws_size,
                              hipStream_t stream) {
    const float* x       = (const float*)d_in[0];
    const float* dte     = (const float*)d_in[1];
    const float* w_gate  = (const float*)d_in[2];
    const float* W_exp   = (const float*)d_in[3];
    const float* b_exp   = (const float*)d_in[4];
    const float* W_sh    = (const float*)d_in[5];
    const float* b_sh    = (const float*)d_in[6];
    const float* ln_g    = (const float*)d_in[7];
    const float* ln_b    = (const float*)d_in[8];
    const float* W_px    = (const float*)d_in[9];
    const float* b_px    = (const float*)d_in[10];
    const float* conv_sh = (const float*)d_in[11];
    const float* W_pxx   = (const float*)d_in[12];
    const float* b_pxx   = (const float*)d_in[13];
    const float* W_dte   = (const float*)d_in[14];
    const float* b_dte   = (const float*)d_in[15];
    const float* W_dteall= (const float*)d_in[16];
    const float* b_dteall= (const float*)d_in[17];
    const float* W_rgb   = (const float*)d_in[18];
    const float* b_rgb   = (const float*)d_in[19];
    const float* W_fx    = (const float*)d_in[20];
    const float* b_fx    = (const float*)d_in[21];
    const float* W_fmod  = (const float*)d_in[22];
    const float* b_fmod  = (const float*)d_in[23];
    const float* W_fxx   = (const float*)d_in[24];
    const float* b_fxx   = (const float*)d_in[25];

    float* out = (float*)d_out;     // [0,1048576) plane + loss at [1048576]

    float* wsf    = (float*)d_ws;
    float* partial= wsf;                         // 2048
    int*   topi   = (int*)(wsf + 2048);          // 128
    float* topg   = wsf + 2176;                  // 128
    float* bias_y = wsf + 2304;                  // 4096
    float* buf_sh = wsf + 8192;                  // 1048576 f32
    u16*   buf_y  = (u16*)(wsf + 8192 + 1048576);
    u16*   t1     = (u16*)(wsf + 8192 + 1048576 + 524288);
    u16*   t2     = (u16*)(wsf + 8192 + 1048576 + 524288*2);

    hipLaunchKernelGGL(k_gate_part, dim3(256), dim3(256), 0, stream, dte, w_gate, partial);
    hipLaunchKernelGGL(k_gate_fin, dim3(1), dim3(256), 0, stream,
                       partial, b_exp, topi, topg, bias_y, out + 1048576);
    hipLaunchKernelGGL(k_gemm3, dim3(768), dim3(256), 0, stream,
                       dte, x, W_sh, b_sh, W_exp, topi, topg, bias_y, W_rgb, b_rgb,
                       buf_sh, buf_y, out);
    hipLaunchKernelGGL(k_lnpx, dim3(512), dim3(256), 0, stream,
                       buf_sh, ln_g, ln_b, W_px, b_px, t1, t2);
    hipLaunchKernelGGL(k_tail, dim3(512), dim3(256), 0, stream,
                       t1, t2, conv_sh, W_pxx, b_pxx, buf_sh, buf_y,
                       W_dte, b_dte, W_dteall, b_dteall,
                       W_fx, b_fx, W_fmod, b_fmod, W_fxx, b_fxx, out);

    (void)in_sizes; (void)n_in; (void)out_size; (void)ws_size;
}